// Round 16
// baseline (2749.574 us; speedup 1.0000x reference)
//
#include <hip/hip_runtime.h>
#include <hip/hip_bf16.h>

#define L_ 2048
#define D_ 1024
#define H_ 16
#define DH_ 64
#define DI_ 4096
#define NL_ 12
#define V_ 32000
#define EPS_ 1e-5f
#define SCALE_ 0.125f
#define LOG2E_ 1.44269504f
#define KBLK 64

typedef __attribute__((ext_vector_type(8))) short short8;
typedef __attribute__((ext_vector_type(4))) float f32x4;
typedef __hip_bfloat16 bf16;

__device__ __forceinline__ void gload_lds16(const void* g, void* l) {
  __builtin_amdgcn_global_load_lds((const __attribute__((address_space(1))) void*)g,
                                   (__attribute__((address_space(3))) void*)l, 16, 0, 0);
}

// swizzle for [row][64 bf16] (128B rows): fold row bits 0-2 into bank bits 2-4.
#define SWZ_(o) ((o) ^ ((((o) >> 7) & 7) << 4))
// swizzle for [row][32 bf16] (64B rows): fold row bits 1-2 into bank bits 2-3.
#define SWZ32_(o) ((o) ^ ((((o) >> 7) & 3) << 4))

// ---------------- 256^2 counted-vmcnt GEMM, BK=32, 64KB LDS (2 blocks/CU) ----------------
__global__ __launch_bounds__(512)
void gemm256(const bf16* __restrict__ A, const bf16* __restrict__ B,
             float* __restrict__ C, const float* __restrict__ bias,
             int lda, int ldb, int ldc, int K)
{
  __shared__ __align__(16) bf16 As[2][256 * 32];
  __shared__ __align__(16) bf16 Bs[2][256 * 32];

  const int gx = gridDim.x;
  const int nwg = gx * gridDim.y;
  const int orig = blockIdx.x + gx * blockIdx.y;
  const int qq = nwg >> 3, rr = nwg & 7;
  const int xcd = orig & 7, sidx = orig >> 3;
  const int lin = (xcd < rr ? xcd * (qq + 1) : rr * (qq + 1) + (xcd - rr) * qq) + sidx;
  const int m0 = (lin % gx) * 256;
  const int n0 = (lin / gx) * 256;

  const int t = threadIdx.x;
  const int lane = t & 63, w = t >> 6;
  const int wm = w >> 2, wn = w & 3;
  const int rl = lane & 15, hi = lane >> 4;

  int srow[2], skb[2];
#pragma unroll
  for (int r = 0; r < 2; ++r) {
    int o = r * 8192 + t * 16;
    int s = SWZ32_(o);
    srow[r] = s >> 6;
    skb[r] = s & 63;
  }

  auto stage = [&](int c, int kt) {
    const int k0 = kt * 32;
#pragma unroll
    for (int r = 0; r < 2; ++r)
      gload_lds16((const char*)A + ((size_t)(m0 + srow[r]) * lda + k0) * 2 + skb[r],
                  (char*)As[c] + r * 8192 + w * 1024);
#pragma unroll
    for (int r = 0; r < 2; ++r)
      gload_lds16((const char*)B + ((size_t)(n0 + srow[r]) * ldb + k0) * 2 + skb[r],
                  (char*)Bs[c] + r * 8192 + w * 1024);
  };

  f32x4 acc[8][4];
#pragma unroll
  for (int i = 0; i < 8; ++i)
#pragma unroll
    for (int j = 0; j < 4; ++j) acc[i][j] = (f32x4){0.f, 0.f, 0.f, 0.f};

  const int NT = K >> 5;
  stage(0, 0);
  stage(1, 1);
  asm volatile("s_waitcnt vmcnt(4)" ::: "memory");
  __builtin_amdgcn_s_barrier();
  asm volatile("" ::: "memory");

  int cur = 0;
  for (int kt = 0; kt < NT; ++kt) {
    short8 b[4];
#pragma unroll
    for (int nf = 0; nf < 4; ++nf) {
      int l = ((wn * 64 + nf * 16 + rl) << 6) + hi * 16;
      b[nf] = *(const short8*)((char*)Bs[cur] + SWZ32_(l));
    }
#pragma unroll
    for (int p = 0; p < 4; ++p) {
      short8 a[2];
#pragma unroll
      for (int i = 0; i < 2; ++i) {
        int l = ((wm * 128 + (2 * p + i) * 16 + rl) << 6) + hi * 16;
        a[i] = *(const short8*)((char*)As[cur] + SWZ32_(l));
      }
      __builtin_amdgcn_s_setprio(1);
#pragma unroll
      for (int i = 0; i < 2; ++i)
#pragma unroll
        for (int nf = 0; nf < 4; ++nf)
          acc[2 * p + i][nf] = __builtin_amdgcn_mfma_f32_16x16x32_bf16(a[i], b[nf], acc[2 * p + i][nf], 0, 0, 0);
      __builtin_amdgcn_s_setprio(0);
      __builtin_amdgcn_sched_barrier(0);
    }
    __builtin_amdgcn_s_barrier();
    asm volatile("" ::: "memory");
    if (kt + 2 < NT) stage(cur, kt + 2);
    if (kt + 1 < NT) {
      if (kt + 2 < NT) asm volatile("s_waitcnt vmcnt(4)" ::: "memory");
      else             asm volatile("s_waitcnt vmcnt(0)" ::: "memory");
      __builtin_amdgcn_s_barrier();
      asm volatile("" ::: "memory");
    }
    cur ^= 1;
  }

#pragma unroll
  for (int mf = 0; mf < 8; ++mf) {
#pragma unroll
    for (int nf = 0; nf < 4; ++nf) {
#pragma unroll
      for (int j = 0; j < 4; ++j) {
        const int m = m0 + wm * 128 + mf * 16 + hi * 4 + j;
        const int n = n0 + wn * 64 + nf * 16 + rl;
        C[(size_t)m * ldc + n] = acc[mf][nf][j] + bias[n];
      }
    }
  }
}

// ---------------- 256x128 counted-vmcnt GEMM (layer GEMMs, 2-buffer) ----------------
template<int EPI>
__global__ __launch_bounds__(512)
void gemm256x128(const bf16* __restrict__ A, const bf16* __restrict__ B,
                 void* __restrict__ C, const float* __restrict__ bias,
                 int lda, int ldb, int ldc, int Kc, long long Cstride)
{
  __shared__ __align__(16) bf16 As[2][256 * 64];
  __shared__ __align__(16) bf16 Bs[2][128 * 64];

  const int gx = gridDim.x;
  const int nwg = gx * gridDim.y;
  const int orig = blockIdx.x + gx * blockIdx.y;
  const int qq = nwg >> 3, rr = nwg & 7;
  const int xcd = orig & 7, sidx = orig >> 3;
  const int lin = (xcd < rr ? xcd * (qq + 1) : rr * (qq + 1) + (xcd - rr) * qq) + sidx;
  const int m0 = (lin % gx) * 256;
  const int n0 = (lin / gx) * 128;

  const int kbeg = blockIdx.z * Kc;
  const size_t czoff = (size_t)blockIdx.z * (size_t)Cstride;

  const int t = threadIdx.x;
  const int lane = t & 63, w = t >> 6;
  const int wm = w >> 1, wn = w & 1;   // 4M x 2N
  const int rl = lane & 15, hi = lane >> 4;

  int srow[4], skb[4];
#pragma unroll
  for (int r = 0; r < 4; ++r) {
    int o = r * 8192 + t * 16;
    int s = SWZ_(o);
    srow[r] = s >> 7;
    skb[r] = s & 127;
  }

  auto stage = [&](int c, int kt) {
    const int k0 = kbeg + kt * 64;
#pragma unroll
    for (int r = 0; r < 4; ++r)
      gload_lds16((const char*)A + ((size_t)(m0 + srow[r]) * lda + k0) * 2 + skb[r],
                  (char*)As[c] + r * 8192 + w * 1024);
#pragma unroll
    for (int r = 0; r < 2; ++r)
      gload_lds16((const char*)B + ((size_t)(n0 + srow[r]) * ldb + k0) * 2 + skb[r],
                  (char*)Bs[c] + r * 8192 + w * 1024);
  };

  f32x4 acc[4][4];
#pragma unroll
  for (int i = 0; i < 4; ++i)
#pragma unroll
    for (int j = 0; j < 4; ++j) acc[i][j] = (f32x4){0.f, 0.f, 0.f, 0.f};

  const int NT = Kc >> 6;
  stage(0, 0);
  stage(1, 1);
  asm volatile("s_waitcnt vmcnt(6)" ::: "memory");
  __builtin_amdgcn_s_barrier();
  asm volatile("" ::: "memory");

  int cur = 0;
  for (int kt = 0; kt < NT; ++kt) {
    short8 b[4][2];
#pragma unroll
    for (int nf = 0; nf < 4; ++nf)
#pragma unroll
      for (int ks = 0; ks < 2; ++ks) {
        int l = ((wn * 64 + nf * 16 + rl) << 7) + ks * 64 + hi * 16;
        b[nf][ks] = *(const short8*)((char*)Bs[cur] + SWZ_(l));
      }
#pragma unroll
    for (int p = 0; p < 4; ++p) {
      short8 a[2];
#pragma unroll
      for (int ks = 0; ks < 2; ++ks) {
        int l = ((wm * 64 + p * 16 + rl) << 7) + ks * 64 + hi * 16;
        a[ks] = *(const short8*)((char*)As[cur] + SWZ_(l));
      }
      __builtin_amdgcn_s_setprio(1);
#pragma unroll
      for (int nf = 0; nf < 4; ++nf) {
        acc[p][nf] = __builtin_amdgcn_mfma_f32_16x16x32_bf16(a[0], b[nf][0], acc[p][nf], 0, 0, 0);
        acc[p][nf] = __builtin_amdgcn_mfma_f32_16x16x32_bf16(a[1], b[nf][1], acc[p][nf], 0, 0, 0);
      }
      __builtin_amdgcn_s_setprio(0);
      __builtin_amdgcn_sched_barrier(0);
    }
    __builtin_amdgcn_s_barrier();
    asm volatile("" ::: "memory");
    if (kt + 2 < NT) stage(cur, kt + 2);
    if (kt + 1 < NT) {
      if (kt + 2 < NT) asm volatile("s_waitcnt vmcnt(6)" ::: "memory");
      else             asm volatile("s_waitcnt vmcnt(0)" ::: "memory");
      __builtin_amdgcn_s_barrier();
      asm volatile("" ::: "memory");
    }
    cur ^= 1;
  }

#pragma unroll
  for (int mf = 0; mf < 4; ++mf) {
#pragma unroll
    for (int nf = 0; nf < 4; ++nf) {
#pragma unroll
      for (int j = 0; j < 4; ++j) {
        const int m = m0 + wm * 64 + mf * 16 + hi * 4 + j;
        const int n = n0 + wn * 64 + nf * 16 + rl;
        if (EPI == 0) {
          float vv = fmaxf(acc[mf][nf][j] + bias[n], 0.f);
          ((bf16*)C)[(size_t)m * ldc + n] = __float2bfloat16(vv);
        } else {
          ((float*)C)[czoff + (size_t)m * ldc + n] = acc[mf][nf][j];
        }
      }
    }
  }
}

// ---------------- 256x128 qkv+pe GEMM (2-buffer, fused V-transpose epilogue) ----------------
__global__ __launch_bounds__(512)
void gemm_qkvpe256(const bf16* __restrict__ Ah, const bf16* __restrict__ Ape,
                   const bf16* __restrict__ Wqkv, const bf16* __restrict__ Wpe,
                   const float* __restrict__ u, const float* __restrict__ v,
                   bf16* __restrict__ QuQv, bf16* __restrict__ Kr, bf16* __restrict__ VT)
{
  __shared__ __align__(16) bf16 As[2][256 * 64];
  __shared__ __align__(16) bf16 Bs[2][128 * 64];

  const int gx = gridDim.x;
  const int nwg = gx * gridDim.y;
  const int orig = blockIdx.x + gx * blockIdx.y;
  const int qq = nwg >> 3, rr = nwg & 7;
  const int xcd = orig & 7, sidx = orig >> 3;
  const int lin = (xcd < rr ? xcd * (qq + 1) : rr * (qq + 1) + (xcd - rr) * qq) + sidx;
  const int m0 = (lin % gx) * 256;
  const int n0 = (lin / gx) * 128;

  const bf16* Ab = (n0 < 3072) ? Ah : Ape;
  const bf16* Bb = (n0 < 3072) ? (Wqkv + (size_t)n0 * D_) : (Wpe + (size_t)(n0 - 3072) * D_);

  const int t = threadIdx.x;
  const int lane = t & 63, w = t >> 6;
  const int wm = w >> 1, wn = w & 1;
  const int rl = lane & 15, hi = lane >> 4;

  int srow[4], skb[4];
#pragma unroll
  for (int r = 0; r < 4; ++r) {
    int o = r * 8192 + t * 16;
    int s = SWZ_(o);
    srow[r] = s >> 7;
    skb[r] = s & 127;
  }

  auto stage = [&](int c, int kt) {
    const int k0 = kt * 64;
#pragma unroll
    for (int r = 0; r < 4; ++r)
      gload_lds16((const char*)Ab + ((size_t)(m0 + srow[r]) * D_ + k0) * 2 + skb[r],
                  (char*)As[c] + r * 8192 + w * 1024);
#pragma unroll
    for (int r = 0; r < 2; ++r)
      gload_lds16((const char*)Bb + ((size_t)srow[r] * D_ + k0) * 2 + skb[r],
                  (char*)Bs[c] + r * 8192 + w * 1024);
  };

  f32x4 acc[4][4];
#pragma unroll
  for (int i = 0; i < 4; ++i)
#pragma unroll
    for (int j = 0; j < 4; ++j) acc[i][j] = (f32x4){0.f, 0.f, 0.f, 0.f};

  const int NT = D_ >> 6;   // 16
  stage(0, 0);
  stage(1, 1);
  asm volatile("s_waitcnt vmcnt(6)" ::: "memory");
  __builtin_amdgcn_s_barrier();
  asm volatile("" ::: "memory");

  int cur = 0;
  for (int kt = 0; kt < NT; ++kt) {
    short8 b[4][2];
#pragma unroll
    for (int nf = 0; nf < 4; ++nf)
#pragma unroll
      for (int ks = 0; ks < 2; ++ks) {
        int l = ((wn * 64 + nf * 16 + rl) << 7) + ks * 64 + hi * 16;
        b[nf][ks] = *(const short8*)((char*)Bs[cur] + SWZ_(l));
      }
#pragma unroll
    for (int p = 0; p < 4; ++p) {
      short8 a[2];
#pragma unroll
      for (int ks = 0; ks < 2; ++ks) {
        int l = ((wm * 64 + p * 16 + rl) << 7) + ks * 64 + hi * 16;
        a[ks] = *(const short8*)((char*)As[cur] + SWZ_(l));
      }
      __builtin_amdgcn_s_setprio(1);
#pragma unroll
      for (int nf = 0; nf < 4; ++nf) {
        acc[p][nf] = __builtin_amdgcn_mfma_f32_16x16x32_bf16(a[0], b[nf][0], acc[p][nf], 0, 0, 0);
        acc[p][nf] = __builtin_amdgcn_mfma_f32_16x16x32_bf16(a[1], b[nf][1], acc[p][nf], 0, 0, 0);
      }
      __builtin_amdgcn_s_setprio(0);
      __builtin_amdgcn_sched_barrier(0);
    }
    __builtin_amdgcn_s_barrier();
    asm volatile("" ::: "memory");
    if (kt + 2 < NT) stage(cur, kt + 2);
    if (kt + 1 < NT) {
      if (kt + 2 < NT) asm volatile("s_waitcnt vmcnt(6)" ::: "memory");
      else             asm volatile("s_waitcnt vmcnt(0)" ::: "memory");
      __builtin_amdgcn_s_barrier();
      asm volatile("" ::: "memory");
    }
    cur ^= 1;
  }

  if (n0 >= 2048 && n0 < 3072) {
    bf16* tb = (bf16*)As;
    __syncthreads();
#pragma unroll
    for (int mf = 0; mf < 4; ++mf) {
#pragma unroll
      for (int nf = 0; nf < 4; ++nf) {
        const int nl = wn * 64 + nf * 16 + rl;
        const int ml = wm * 64 + mf * 16 + hi * 4;
        unsigned long long pk = 0;
#pragma unroll
        for (int j = 0; j < 4; ++j) {
          unsigned short b16 = __bfloat16_as_ushort(__float2bfloat16(acc[mf][nf][j]));
          pk |= (unsigned long long)b16 << (16 * j);
        }
        int o = (nl << 9) + (ml << 1);
        *(unsigned long long*)((char*)tb + (o ^ ((nl & 7) << 4))) = pk;
      }
    }
    __syncthreads();
    const int dbase = n0 - 2048;
#pragma unroll
    for (int i = 0; i < 8; ++i) {
      int c = i * 512 + t;
      int dl = c >> 5, mc = c & 31;
      int o = (dl << 9) + (mc << 4);
      short8 vv = *(const short8*)((char*)tb + (o ^ ((dl & 7) << 4)));
      *(short8*)(VT + (size_t)(dbase + dl) * L_ + m0 + mc * 8) = vv;
    }
  } else {
#pragma unroll
    for (int mf = 0; mf < 4; ++mf) {
#pragma unroll
      for (int nf = 0; nf < 4; ++nf) {
#pragma unroll
        for (int j = 0; j < 4; ++j) {
          const int m = m0 + wm * 64 + mf * 16 + hi * 4 + j;
          const int n = n0 + wn * 64 + nf * 16 + rl;
          float x = acc[mf][nf][j];
          if (n < 1024) {
            const int h = n >> 6, d = n & 63;
            size_t b = ((size_t)h * L_ + m) * 128;
            QuQv[b + d]      = __float2bfloat16((x + u[n]) * SCALE_);
            QuQv[b + 64 + d] = __float2bfloat16((x + v[n]) * SCALE_);
          } else if (n < 2048) {
            const int n2 = n - 1024;
            Kr[(((size_t)(n2 >> 6)) * L_ + m) * 128 + (n2 & 63)] = __float2bfloat16(x);
          } else {
            const int c = n - 3072;
            Kr[(((size_t)(c >> 6)) * L_ + m) * 128 + 64 + (c & 63)] = __float2bfloat16(x);
          }
        }
      }
    }
  }
}

// Fused causal attention: LDS-staged K/V (KBLK=64), T14 async-STAGE, setprio.
__global__ __launch_bounds__(256)
void attn_fused(const bf16* __restrict__ QuQv, const bf16* __restrict__ Kr,
                const bf16* __restrict__ VT, bf16* __restrict__ av)
{
  __shared__ __align__(16) bf16 Kt[KBLK * 128];
  __shared__ __align__(16) bf16 Vt[DH_ * KBLK];
  __shared__ __align__(16) bf16 Pt[4][16 * KBLK];

  const int bid = blockIdx.x;
  const int tile = (bid < 256) ? (31 - (bid >> 4)) : ((bid - 256) >> 4);
  const int head = bid & 15;
  const int q0 = tile * 64;
  const int t = threadIdx.x, lane = t & 63, w = t >> 6;
  const int rl = lane & 15, hi = lane >> 4;

  const bf16* Qh = QuQv + (size_t)head * L_ * 128;
  const bf16* Kh = Kr   + (size_t)head * L_ * 128;
  const bf16* Vh = VT   + (size_t)head * DH_ * L_;

  const int qw0 = q0 + w * 16;

  short8 qf[4];
#pragma unroll
  for (int ks = 0; ks < 4; ++ks)
    qf[ks] = *(const short8*)(Qh + (size_t)(qw0 + rl) * 128 + ks * 32 + hi * 8);

  f32x4 o[4];
  float m_r[4], l_r[4];
#pragma unroll
  for (int j = 0; j < 4; ++j) { m_r[j] = -INFINITY; l_r[j] = 0.f; }
#pragma unroll
  for (int fn = 0; fn < 4; ++fn) o[fn] = (f32x4){0.f, 0.f, 0.f, 0.f};

  short8 kreg[4], vreg[2];
  auto load_regs = [&](int k0) {
#pragma unroll
    for (int i = 0; i < 4; ++i) {
      int c = i * 256 + t;
      int row = c >> 4, d8 = (c & 15) << 3;
      kreg[i] = *(const short8*)(Kh + (size_t)(k0 + row) * 128 + d8);
    }
#pragma unroll
    for (int i = 0; i < 2; ++i) {
      int c = i * 256 + t;
      int d = c >> 3, k8 = (c & 7) << 3;
      vreg[i] = *(const short8*)(Vh + (size_t)d * L_ + k0 + k8);
    }
  };
  auto write_lds = [&]() {
#pragma unroll
    for (int i = 0; i < 4; ++i) {
      int c = i * 256 + t;
      int row = c >> 4, d8 = (c & 15) << 3;
      int off = (row << 8) + (((d8 << 1)) ^ ((row & 7) << 4));
      *(short8*)((char*)Kt + off) = kreg[i];
    }
#pragma unroll
    for (int i = 0; i < 2; ++i) {
      int c = i * 256 + t;
      int d = c >> 3, k8 = (c & 7) << 3;
      int off = (d << 7) + (((k8 << 1)) ^ ((d & 7) << 4));
      *(short8*)((char*)Vt + off) = vreg[i];
    }
  };

  load_regs(0);
  write_lds();
  __syncthreads();

  const int kend = q0 + 64;
  for (int k0 = 0; k0 < kend; k0 += KBLK) {
    const bool more = (k0 + KBLK) < kend;
    if (more) load_regs(k0 + KBLK);

    if (k0 <= qw0 + 15) {
      f32x4 s[4];
#pragma unroll
      for (int fn = 0; fn < 4; ++fn) s[fn] = (f32x4){0.f, 0.f, 0.f, 0.f};
      __builtin_amdgcn_s_setprio(1);
#pragma unroll
      for (int fn = 0; fn < 4; ++fn) {
        const int krow = fn * 16 + rl;
#pragma unroll
        for (int ks = 0; ks < 4; ++ks) {
          short8 kf = *(const short8*)((char*)Kt + (krow << 8) +
                        ((((ks * 32 + hi * 8) << 1)) ^ ((krow & 7) << 4)));
          s[fn] = __builtin_amdgcn_mfma_f32_16x16x32_bf16(qf[ks], kf, s[fn], 0, 0, 0);
        }
      }
      __builtin_amdgcn_s_setprio(0);
      if (k0 + KBLK > q0) {
#pragma unroll
        for (int fn = 0; fn < 4; ++fn) {
          const int key = k0 + fn * 16 + rl;
#pragma unroll
          for (int j = 0; j < 4; ++j)
            if (key > qw0 + hi * 4 + j) s[fn][j] = -1e30f;
        }
      }
      float mx[4];
#pragma unroll
      for (int j = 0; j < 4; ++j)
        mx[j] = fmaxf(fmaxf(s[0][j], s[1][j]), fmaxf(s[2][j], s[3][j]));
#pragma unroll
      for (int off = 1; off < 16; off <<= 1)
#pragma unroll
        for (int j = 0; j < 4; ++j) mx[j] = fmaxf(mx[j], __shfl_xor(mx[j], off));
      float sf[4];
#pragma unroll
      for (int j = 0; j < 4; ++j) {
        float mn = fmaxf(m_r[j], mx[j]);
        sf[j] = exp2f((m_r[j] - mn) * LOG2E_);
        m_r[j] = mn;
      }
      float rs[4] = {0.f, 0.f, 0.f, 0.f};
#pragma unroll
      for (int fn = 0; fn < 4; ++fn) {
#pragma unroll
        for (int j = 0; j < 4; ++j) {
          float p = exp2f((s[fn][j] - m_r[j]) * LOG2E_);
          rs[j] += p;
          int row = hi * 4 + j;
          *(bf16*)((char*)Pt[w] + (row << 7) +
                   ((((fn * 16 + rl) << 1)) ^ ((row & 7) << 4))) = __float2bfloat16(p);
        }
      }
#pragma unroll
      for (int off = 1; off < 16; off <<= 1)
#pragma unroll
        for (int j = 0; j < 4; ++j) rs[j] += __shfl_xor(rs[j], off);
#pragma unroll
      for (int j = 0; j < 4; ++j) l_r[j] = l_r[j] * sf[j] + rs[j];
#pragma unroll
      for (int fn = 0; fn < 4; ++fn)
#pragma unroll
        for (int j = 0; j < 4; ++j) o[fn][j] *= sf[j];

      __builtin_amdgcn_s_setprio(1);
#pragma unroll
      for (int ks2 = 0; ks2 < 2; ++ks2) {
        short8 pa = *(const short8*)((char*)Pt[w] + (rl << 7) +
                      ((ks2 * 64 + hi * 16) ^ ((rl & 7) << 4)));
#pragma unroll
        for (int fn = 0; fn < 4; ++fn) {
          const int drow = fn * 16 + rl;
          short8 vf = *(const short8*)((char*)Vt + (drow << 7) +
                        ((ks2 * 64 + hi * 16) ^ ((drow & 7) << 4)));
          o[fn] = __builtin_amdgcn_mfma_f32_16x16x32_bf16(pa, vf, o[fn], 0, 0, 0);
        }
      }
      __builtin_amdgcn_s_setprio(0);
    }

    if (more) {
      __syncthreads();
      write_lds();
      __syncthreads();
    }
  }

#pragma unroll
  for (int fn = 0; fn < 4; ++fn) {
#pragma unroll
    for (int j = 0; j < 4; ++j) {
      int q = qw0 + hi * 4 + j;
      float vv = o[fn][j] / l_r[j];
      av[(size_t)q * D_ + head * 64 + fn * 16 + rl] = __float2bfloat16(vv);
    }
  }
}

__global__ __launch_bounds__(256)
void embed_k(const int* __restrict__ X, const float* __restrict__ emb,
             float* __restrict__ hout, bf16* __restrict__ hbout)
{
  int idx = blockIdx.x * 256 + threadIdx.x;
  if (idx >= L_ * D_) return;
  int tpos = idx >> 10, d = idx & 1023;
  float vv = emb[(size_t)X[tpos] * D_ + d];
  hout[idx] = vv;
  hbout[idx] = __float2bfloat16(vv);
}

__global__ __launch_bounds__(256)
void pe_k(bf16* __restrict__ pe)
{
  int idx = blockIdx.x * 256 + threadIdx.x;
  if (idx >= L_ * D_) return;
  int k = idx >> 10, i = idx & 1023;
  int f = (i < 512) ? i : (i - 512);
  float invf = exp2f(-(float)(2 * f) * (13.28771238f / 1024.f));
  float pp = (float)(L_ - 1 - k) * invf;
  float vv = (i < 512) ? sinf(pp) : cosf(pp);
  pe[idx] = __float2bfloat16(vv);
}

__global__ __launch_bounds__(256)
void cast_all(const float* __restrict__ wqkv, const float* __restrict__ wpe,
              const float* __restrict__ wout, const float* __restrict__ w1,
              const float* __restrict__ w2,
              bf16* __restrict__ dqkv, bf16* __restrict__ dpe, bf16* __restrict__ dout,
              bf16* __restrict__ d1, bf16* __restrict__ d2)
{
  const int n4 = 13631488 / 4;
  for (int i = blockIdx.x * 256 + threadIdx.x; i < n4; i += gridDim.x * 256) {
    int j = i * 4;
    const float* src; bf16* dst; int o;
    if (j < 3145728)      { src = wqkv; dst = dqkv; o = j; }
    else if (j < 4194304) { src = wpe;  dst = dpe;  o = j - 3145728; }
    else if (j < 5242880) { src = wout; dst = dout; o = j - 4194304; }
    else if (j < 9437184) { src = w1;   dst = d1;   o = j - 5242880; }
    else                  { src = w2;   dst = d2;   o = j - 9437184; }
    float4 vv = *(const float4*)(src + o);
    dst[o + 0] = __float2bfloat16(vv.x);
    dst[o + 1] = __float2bfloat16(vv.y);
    dst[o + 2] = __float2bfloat16(vv.z);
    dst[o + 3] = __float2bfloat16(vv.w);
  }
}

__global__ __launch_bounds__(256)
void cast_bf4(const float* __restrict__ in, bf16* __restrict__ out, long long n4)
{
  for (long long i = (long long)blockIdx.x * 256 + threadIdx.x; i < n4; i += (long long)gridDim.x * 256) {
    float4 vv = *(const float4*)(in + i * 4);
    out[i * 4 + 0] = __float2bfloat16(vv.x);
    out[i * 4 + 1] = __float2bfloat16(vv.y);
    out[i * 4 + 2] = __float2bfloat16(vv.z);
    out[i * 4 + 3] = __float2bfloat16(vv.w);
  }
}

__global__ __launch_bounds__(256)
void ln_residual(const float* __restrict__ resid, const float* __restrict__ parts,
                 int nparts, long long pstride, const float* __restrict__ bias,
                 float* __restrict__ hout, bf16* __restrict__ hbout)
{
  const int row = blockIdx.x;
  const int t = threadIdx.x;
  const int lane = t & 63, w = t >> 6;
  const size_t base = (size_t)row * D_;
  __shared__ float rs[4], rs2[4];
  float4 xv = *(const float4*)(resid + base + t * 4);
  for (int p = 0; p < nparts; ++p) {
    float4 pv = *(const float4*)(parts + (size_t)p * pstride + base + t * 4);
    xv.x += pv.x; xv.y += pv.y; xv.z += pv.z; xv.w += pv.w;
  }
  if (bias) {
    float4 bv = *(const float4*)(bias + t * 4);
    xv.x += bv.x; xv.y += bv.y; xv.z += bv.z; xv.w += bv.w;
  }
  float s = xv.x + xv.y + xv.z + xv.w;
  float s2 = xv.x * xv.x + xv.y * xv.y + xv.z * xv.z + xv.w * xv.w;
#pragma unroll
  for (int off = 32; off; off >>= 1) {
    s += __shfl_down(s, off);
    s2 += __shfl_down(s2, off);
  }
  if (lane == 0) { rs[w] = s; rs2[w] = s2; }
  __syncthreads();
  float S = rs[0] + rs[1] + rs[2] + rs[3];
  float S2 = rs2[0] + rs2[1] + rs2[2] + rs2[3];
  float mean = S * (1.f / D_);
  float var = S2 * (1.f / D_) - mean * mean;
  float inv = 1.f / sqrtf(var + EPS_);
  float4 y;
  y.x = (xv.x - mean) * inv;
  y.y = (xv.y - mean) * inv;
  y.z = (xv.z - mean) * inv;
  y.w = (xv.w - mean) * inv;
  *(float4*)(hout + base + t * 4) = y;
  __hip_bfloat162 p0, p1;
  p0.x = __float2bfloat16(y.x); p0.y = __float2bfloat16(y.y);
  p1.x = __float2bfloat16(y.z); p1.y = __float2bfloat16(y.w);
  *(__hip_bfloat162*)(hbout + base + t * 4)     = p0;
  *(__hip_bfloat162*)(hbout + base + t * 4 + 2) = p1;
}

extern "C" void kernel_launch(void* const* d_in, const int* in_sizes, int n_in,
                              void* d_out, int out_size, void* d_ws, size_t ws_size,
                              hipStream_t stream)
{
  (void)in_sizes; (void)n_in; (void)out_size; (void)ws_size;
  const int*   X    = (const int*)d_in[0];
  const float* emb  = (const float*)d_in[2];
  const float* u    = (const float*)d_in[3];
  const float* v    = (const float*)d_in[4];
  const float* Wqkv = (const float*)d_in[5];
  const float* Wpe  = (const float*)d_in[6];
  const float* Wout = (const float*)d_in[7];
  const float* W1   = (const float*)d_in[8];
  const float* b1   = (const float*)d_in[9];
  const float* W2   = (const float*)d_in[10];
  const float* b2   = (const float*)d_in[11];
  const float* Wc   = (const float*)d_in[12];
  const float* bc   = (const float*)d_in[13];
  float* out = (float*)d_out;

  size_t off = 0;
  auto alloc = [&](size_t bytes) {
    void* p = (char*)d_ws + off;
    off += (bytes + 255) & ~(size_t)255;
    return p;
  };
  float* h_f32   = (float*)alloc((size_t)L_ * D_ * 4);
  bf16*  h_bf    = (bf16*) alloc((size_t)L_ * D_ * 2);
  bf16*  pe_bf   = (bf16*) alloc((size_t)L_ * D_ * 2);
  bf16*  QuQv    = (bf16*) alloc((size_t)H_ * L_ * 128 * 2);
  bf16*  Kr      = (bf16*) alloc((size_t)H_ * L_ * 128 * 2);
  bf16*  VT      = (bf16*) alloc((size_t)H_ * DH_ * L_ * 2);
  bf16*  av_bf   = (bf16*) alloc((size_t)L_ * D_ * 2);
  float* part_f  = (float*)alloc((size_t)4 * L_ * D_ * 4);
  bf16*  ff1_bf  = (bf16*) alloc((size_t)L_ * DI_ * 2);
  bf16*  Wc_bf   = (bf16*) alloc((size_t)V_ * D_ * 2);
  bf16*  Wqkv_bf = (bf16*) alloc((size_t)3 * D_ * D_ * 2);
  bf16*  Wpe_bf  = (bf16*) alloc((size_t)D_ * D_ * 2);
  bf16*  Wout_bf = (bf16*) alloc((size_t)D_ * D_ * 2);
  bf16*  W1_bf   = (bf16*) alloc((size_t)DI_ * D_ * 2);
  bf16*  W2_bf   = (bf16*) alloc((size_t)D_ * DI_ * 2);

  const int eb = (L_ * D_ + 255) / 256;
  const long long LD = (long long)L_ * D_;

  embed_k<<<eb, 256, 0, stream>>>(X, emb, h_f32, h_bf);
  pe_k<<<eb, 256, 0, stream>>>(pe_bf);

  dim3 gqkvpe(L_ / 256, 4096 / 128, 1);
  dim3 gout (L_ / 256, D_ / 128, 4);
  dim3 gff1 (L_ / 256, DI_ / 128, 1);

  for (int l = 0; l < NL_; ++l) {
    cast_all<<<2048, 256, 0, stream>>>(
        Wqkv + (size_t)l * 3 * D_ * D_, Wpe + (size_t)l * D_ * D_,
        Wout + (size_t)l * D_ * D_, W1 + (size_t)l * DI_ * D_, W2 + (size_t)l * D_ * DI_,
        Wqkv_bf, Wpe_bf, Wout_bf, W1_bf, W2_bf);

    gemm_qkvpe256<<<gqkvpe, 512, 0, stream>>>(h_bf, pe_bf, Wqkv_bf, Wpe_bf, u, v, QuQv, Kr, VT);

    attn_fused<<<512, 256, 0, stream>>>(QuQv, Kr, VT, av_bf);

    gemm256x128<1><<<gout, 512, 0, stream>>>(av_bf, Wout_bf, part_f, nullptr,
        D_, D_, D_, 256, LD);
    ln_residual<<<L_, 256, 0, stream>>>(h_f32, part_f, 4, LD, nullptr, h_f32, h_bf);

    gemm256x128<0><<<gff1, 512, 0, stream>>>(h_bf, W1_bf, ff1_bf, b1 + (size_t)l * DI_,
        D_, D_, DI_, D_, 0);

    gemm256x128<1><<<gout, 512, 0, stream>>>(ff1_bf, W2_bf, part_f, nullptr,
        DI_, DI_, D_, 1024, LD);
    ln_residual<<<L_, 256, 0, stream>>>(h_f32, part_f, 4, LD, b2 + (size_t)l * D_, h_f32, h_bf);
  }

  cast_bf4<<<2048, 256, 0, stream>>>(Wc, Wc_bf, (long long)V_ * D_ / 4);
  dim3 gl(L_ / 256, V_ / 256, 1);
  gemm256<<<gl, 512, 0, stream>>>(h_bf, Wc_bf, out, bc, D_, D_, V_, D_);
}

// Round 17
// 2728.191 us; speedup vs baseline: 1.0078x; 1.0078x over previous
//
#include <hip/hip_runtime.h>
#include <hip/hip_bf16.h>

#define L_ 2048
#define D_ 1024
#define H_ 16
#define DH_ 64
#define DI_ 4096
#define NL_ 12
#define V_ 32000
#define EPS_ 1e-5f
#define SCALE_ 0.125f
#define LOG2E_ 1.44269504f
#define KBLK 64

typedef __attribute__((ext_vector_type(8))) short short8;
typedef __attribute__((ext_vector_type(4))) float f32x4;
typedef __hip_bfloat16 bf16;

__device__ __forceinline__ void gload_lds16(const void* g, void* l) {
  __builtin_amdgcn_global_load_lds((const __attribute__((address_space(1))) void*)g,
                                   (__attribute__((address_space(3))) void*)l, 16, 0, 0);
}

// swizzle for [row][64 bf16] (128B rows): fold row bits 0-2 into bank bits 2-4. Involution.
#define SWZ_(o) ((o) ^ ((((o) >> 7) & 7) << 4))

// ---------------- 256^2 counted-vmcnt GEMM (logits), BK=64 ----------------
__global__ __launch_bounds__(512)
void gemm256(const bf16* __restrict__ A, const bf16* __restrict__ B,
             float* __restrict__ C, const float* __restrict__ bias,
             int lda, int ldb, int ldc, int K)
{
  __shared__ __align__(16) bf16 As[2][256 * 64];
  __shared__ __align__(16) bf16 Bs[2][256 * 64];

  const int gx = gridDim.x;
  const int nwg = gx * gridDim.y;
  const int orig = blockIdx.x + gx * blockIdx.y;
  const int qq = nwg >> 3, rr = nwg & 7;
  const int xcd = orig & 7, sidx = orig >> 3;
  const int lin = (xcd < rr ? xcd * (qq + 1) : rr * (qq + 1) + (xcd - rr) * qq) + sidx;
  const int m0 = (lin % gx) * 256;
  const int n0 = (lin / gx) * 256;

  const int t = threadIdx.x;
  const int lane = t & 63, w = t >> 6;
  const int wm = w >> 2, wn = w & 3;
  const int rl = lane & 15, hi = lane >> 4;

  int srow[4], skb[4];
#pragma unroll
  for (int r = 0; r < 4; ++r) {
    int o = r * 8192 + t * 16;
    int s = SWZ_(o);
    srow[r] = s >> 7;
    skb[r] = s & 127;
  }

  auto stage = [&](int c, int kt) {
    const int k0 = kt * 64;
#pragma unroll
    for (int r = 0; r < 4; ++r)
      gload_lds16((const char*)A + ((size_t)(m0 + srow[r]) * lda + k0) * 2 + skb[r],
                  (char*)As[c] + r * 8192 + w * 1024);
#pragma unroll
    for (int r = 0; r < 4; ++r)
      gload_lds16((const char*)B + ((size_t)(n0 + srow[r]) * ldb + k0) * 2 + skb[r],
                  (char*)Bs[c] + r * 8192 + w * 1024);
  };

  f32x4 acc[8][4];
#pragma unroll
  for (int i = 0; i < 8; ++i)
#pragma unroll
    for (int j = 0; j < 4; ++j) acc[i][j] = (f32x4){0.f, 0.f, 0.f, 0.f};

  const int NT = K >> 6;
  stage(0, 0);
  stage(1, 1);
  asm volatile("s_waitcnt vmcnt(8)" ::: "memory");
  __builtin_amdgcn_s_barrier();
  asm volatile("" ::: "memory");

  int cur = 0;
  for (int kt = 0; kt < NT; ++kt) {
    short8 b[4][2];
#pragma unroll
    for (int nf = 0; nf < 4; ++nf)
#pragma unroll
      for (int ks = 0; ks < 2; ++ks) {
        int l = ((wn * 64 + nf * 16 + rl) << 7) + ks * 64 + hi * 16;
        b[nf][ks] = *(const short8*)((char*)Bs[cur] + SWZ_(l));
      }
#pragma unroll
    for (int p = 0; p < 4; ++p) {
      short8 a[2][2];
#pragma unroll
      for (int i = 0; i < 2; ++i)
#pragma unroll
        for (int ks = 0; ks < 2; ++ks) {
          int l = ((wm * 128 + (2 * p + i) * 16 + rl) << 7) + ks * 64 + hi * 16;
          a[i][ks] = *(const short8*)((char*)As[cur] + SWZ_(l));
        }
      __builtin_amdgcn_s_setprio(1);
#pragma unroll
      for (int i = 0; i < 2; ++i)
#pragma unroll
        for (int nf = 0; nf < 4; ++nf) {
          acc[2 * p + i][nf] = __builtin_amdgcn_mfma_f32_16x16x32_bf16(a[i][0], b[nf][0], acc[2 * p + i][nf], 0, 0, 0);
          acc[2 * p + i][nf] = __builtin_amdgcn_mfma_f32_16x16x32_bf16(a[i][1], b[nf][1], acc[2 * p + i][nf], 0, 0, 0);
        }
      __builtin_amdgcn_s_setprio(0);
      __builtin_amdgcn_sched_barrier(0);
    }
    __builtin_amdgcn_s_barrier();
    asm volatile("" ::: "memory");
    if (kt + 2 < NT) stage(cur, kt + 2);
    if (kt + 1 < NT) {
      if (kt + 2 < NT) asm volatile("s_waitcnt vmcnt(8)" ::: "memory");
      else             asm volatile("s_waitcnt vmcnt(0)" ::: "memory");
      __builtin_amdgcn_s_barrier();
      asm volatile("" ::: "memory");
    }
    cur ^= 1;
  }

#pragma unroll
  for (int mf = 0; mf < 8; ++mf) {
#pragma unroll
    for (int nf = 0; nf < 4; ++nf) {
#pragma unroll
      for (int j = 0; j < 4; ++j) {
        const int m = m0 + wm * 128 + mf * 16 + hi * 4 + j;
        const int n = n0 + wn * 64 + nf * 16 + rl;
        C[(size_t)m * ldc + n] = acc[mf][nf][j] + bias[n];
      }
    }
  }
}

// ---------------- 256x128 counted-vmcnt GEMM (layer GEMMs, 2-buffer) ----------------
template<int EPI>
__global__ __launch_bounds__(512)
void gemm256x128(const bf16* __restrict__ A, const bf16* __restrict__ B,
                 void* __restrict__ C, const float* __restrict__ bias,
                 int lda, int ldb, int ldc, int Kc, long long Cstride)
{
  __shared__ __align__(16) bf16 As[2][256 * 64];
  __shared__ __align__(16) bf16 Bs[2][128 * 64];

  const int gx = gridDim.x;
  const int nwg = gx * gridDim.y;
  const int orig = blockIdx.x + gx * blockIdx.y;
  const int qq = nwg >> 3, rr = nwg & 7;
  const int xcd = orig & 7, sidx = orig >> 3;
  const int lin = (xcd < rr ? xcd * (qq + 1) : rr * (qq + 1) + (xcd - rr) * qq) + sidx;
  const int m0 = (lin % gx) * 256;
  const int n0 = (lin / gx) * 128;

  const int kbeg = blockIdx.z * Kc;
  const size_t czoff = (size_t)blockIdx.z * (size_t)Cstride;

  const int t = threadIdx.x;
  const int lane = t & 63, w = t >> 6;
  const int wm = w >> 1, wn = w & 1;   // 4M x 2N
  const int rl = lane & 15, hi = lane >> 4;

  int srow[4], skb[4];
#pragma unroll
  for (int r = 0; r < 4; ++r) {
    int o = r * 8192 + t * 16;
    int s = SWZ_(o);
    srow[r] = s >> 7;
    skb[r] = s & 127;
  }

  auto stage = [&](int c, int kt) {
    const int k0 = kbeg + kt * 64;
#pragma unroll
    for (int r = 0; r < 4; ++r)
      gload_lds16((const char*)A + ((size_t)(m0 + srow[r]) * lda + k0) * 2 + skb[r],
                  (char*)As[c] + r * 8192 + w * 1024);
#pragma unroll
    for (int r = 0; r < 2; ++r)
      gload_lds16((const char*)B + ((size_t)(n0 + srow[r]) * ldb + k0) * 2 + skb[r],
                  (char*)Bs[c] + r * 8192 + w * 1024);
  };

  f32x4 acc[4][4];
#pragma unroll
  for (int i = 0; i < 4; ++i)
#pragma unroll
    for (int j = 0; j < 4; ++j) acc[i][j] = (f32x4){0.f, 0.f, 0.f, 0.f};

  const int NT = Kc >> 6;
  stage(0, 0);
  stage(1, 1);
  asm volatile("s_waitcnt vmcnt(6)" ::: "memory");
  __builtin_amdgcn_s_barrier();
  asm volatile("" ::: "memory");

  int cur = 0;
  for (int kt = 0; kt < NT; ++kt) {
    short8 b[4][2];
#pragma unroll
    for (int nf = 0; nf < 4; ++nf)
#pragma unroll
      for (int ks = 0; ks < 2; ++ks) {
        int l = ((wn * 64 + nf * 16 + rl) << 7) + ks * 64 + hi * 16;
        b[nf][ks] = *(const short8*)((char*)Bs[cur] + SWZ_(l));
      }
#pragma unroll
    for (int p = 0; p < 4; ++p) {
      short8 a[2];
#pragma unroll
      for (int ks = 0; ks < 2; ++ks) {
        int l = ((wm * 64 + p * 16 + rl) << 7) + ks * 64 + hi * 16;
        a[ks] = *(const short8*)((char*)As[cur] + SWZ_(l));
      }
      __builtin_amdgcn_s_setprio(1);
#pragma unroll
      for (int nf = 0; nf < 4; ++nf) {
        acc[p][nf] = __builtin_amdgcn_mfma_f32_16x16x32_bf16(a[0], b[nf][0], acc[p][nf], 0, 0, 0);
        acc[p][nf] = __builtin_amdgcn_mfma_f32_16x16x32_bf16(a[1], b[nf][1], acc[p][nf], 0, 0, 0);
      }
      __builtin_amdgcn_s_setprio(0);
      __builtin_amdgcn_sched_barrier(0);
    }
    __builtin_amdgcn_s_barrier();
    asm volatile("" ::: "memory");
    if (kt + 2 < NT) stage(cur, kt + 2);
    if (kt + 1 < NT) {
      if (kt + 2 < NT) asm volatile("s_waitcnt vmcnt(6)" ::: "memory");
      else             asm volatile("s_waitcnt vmcnt(0)" ::: "memory");
      __builtin_amdgcn_s_barrier();
      asm volatile("" ::: "memory");
    }
    cur ^= 1;
  }

#pragma unroll
  for (int mf = 0; mf < 4; ++mf) {
#pragma unroll
    for (int nf = 0; nf < 4; ++nf) {
#pragma unroll
      for (int j = 0; j < 4; ++j) {
        const int m = m0 + wm * 64 + mf * 16 + hi * 4 + j;
        const int n = n0 + wn * 64 + nf * 16 + rl;
        if (EPI == 0) {
          float vv = fmaxf(acc[mf][nf][j] + bias[n], 0.f);
          ((bf16*)C)[(size_t)m * ldc + n] = __float2bfloat16(vv);
        } else {
          ((float*)C)[czoff + (size_t)m * ldc + n] = acc[mf][nf][j];
        }
      }
    }
  }
}

// ---------------- 256x128 qkv+pe GEMM (2-buffer, fused V-transpose epilogue) ----------------
__global__ __launch_bounds__(512)
void gemm_qkvpe256(const bf16* __restrict__ Ah, const bf16* __restrict__ Ape,
                   const bf16* __restrict__ Wqkv, const bf16* __restrict__ Wpe,
                   const float* __restrict__ u, const float* __restrict__ v,
                   bf16* __restrict__ QuQv, bf16* __restrict__ Kr, bf16* __restrict__ VT)
{
  __shared__ __align__(16) bf16 As[2][256 * 64];
  __shared__ __align__(16) bf16 Bs[2][128 * 64];

  const int gx = gridDim.x;
  const int nwg = gx * gridDim.y;
  const int orig = blockIdx.x + gx * blockIdx.y;
  const int qq = nwg >> 3, rr = nwg & 7;
  const int xcd = orig & 7, sidx = orig >> 3;
  const int lin = (xcd < rr ? xcd * (qq + 1) : rr * (qq + 1) + (xcd - rr) * qq) + sidx;
  const int m0 = (lin % gx) * 256;
  const int n0 = (lin / gx) * 128;

  const bf16* Ab = (n0 < 3072) ? Ah : Ape;
  const bf16* Bb = (n0 < 3072) ? (Wqkv + (size_t)n0 * D_) : (Wpe + (size_t)(n0 - 3072) * D_);

  const int t = threadIdx.x;
  const int lane = t & 63, w = t >> 6;
  const int wm = w >> 1, wn = w & 1;
  const int rl = lane & 15, hi = lane >> 4;

  int srow[4], skb[4];
#pragma unroll
  for (int r = 0; r < 4; ++r) {
    int o = r * 8192 + t * 16;
    int s = SWZ_(o);
    srow[r] = s >> 7;
    skb[r] = s & 127;
  }

  auto stage = [&](int c, int kt) {
    const int k0 = kt * 64;
#pragma unroll
    for (int r = 0; r < 4; ++r)
      gload_lds16((const char*)Ab + ((size_t)(m0 + srow[r]) * D_ + k0) * 2 + skb[r],
                  (char*)As[c] + r * 8192 + w * 1024);
#pragma unroll
    for (int r = 0; r < 2; ++r)
      gload_lds16((const char*)Bb + ((size_t)srow[r] * D_ + k0) * 2 + skb[r],
                  (char*)Bs[c] + r * 8192 + w * 1024);
  };

  f32x4 acc[4][4];
#pragma unroll
  for (int i = 0; i < 4; ++i)
#pragma unroll
    for (int j = 0; j < 4; ++j) acc[i][j] = (f32x4){0.f, 0.f, 0.f, 0.f};

  const int NT = D_ >> 6;   // 16
  stage(0, 0);
  stage(1, 1);
  asm volatile("s_waitcnt vmcnt(6)" ::: "memory");
  __builtin_amdgcn_s_barrier();
  asm volatile("" ::: "memory");

  int cur = 0;
  for (int kt = 0; kt < NT; ++kt) {
    short8 b[4][2];
#pragma unroll
    for (int nf = 0; nf < 4; ++nf)
#pragma unroll
      for (int ks = 0; ks < 2; ++ks) {
        int l = ((wn * 64 + nf * 16 + rl) << 7) + ks * 64 + hi * 16;
        b[nf][ks] = *(const short8*)((char*)Bs[cur] + SWZ_(l));
      }
#pragma unroll
    for (int p = 0; p < 4; ++p) {
      short8 a[2];
#pragma unroll
      for (int ks = 0; ks < 2; ++ks) {
        int l = ((wm * 64 + p * 16 + rl) << 7) + ks * 64 + hi * 16;
        a[ks] = *(const short8*)((char*)As[cur] + SWZ_(l));
      }
      __builtin_amdgcn_s_setprio(1);
#pragma unroll
      for (int nf = 0; nf < 4; ++nf) {
        acc[p][nf] = __builtin_amdgcn_mfma_f32_16x16x32_bf16(a[0], b[nf][0], acc[p][nf], 0, 0, 0);
        acc[p][nf] = __builtin_amdgcn_mfma_f32_16x16x32_bf16(a[1], b[nf][1], acc[p][nf], 0, 0, 0);
      }
      __builtin_amdgcn_s_setprio(0);
      __builtin_amdgcn_sched_barrier(0);
    }
    __builtin_amdgcn_s_barrier();
    asm volatile("" ::: "memory");
    if (kt + 2 < NT) stage(cur, kt + 2);
    if (kt + 1 < NT) {
      if (kt + 2 < NT) asm volatile("s_waitcnt vmcnt(6)" ::: "memory");
      else             asm volatile("s_waitcnt vmcnt(0)" ::: "memory");
      __builtin_amdgcn_s_barrier();
      asm volatile("" ::: "memory");
    }
    cur ^= 1;
  }

  if (n0 >= 2048 && n0 < 3072) {
    bf16* tb = (bf16*)As;
    __syncthreads();
#pragma unroll
    for (int mf = 0; mf < 4; ++mf) {
#pragma unroll
      for (int nf = 0; nf < 4; ++nf) {
        const int nl = wn * 64 + nf * 16 + rl;
        const int ml = wm * 64 + mf * 16 + hi * 4;
        unsigned long long pk = 0;
#pragma unroll
        for (int j = 0; j < 4; ++j) {
          unsigned short b16 = __bfloat16_as_ushort(__float2bfloat16(acc[mf][nf][j]));
          pk |= (unsigned long long)b16 << (16 * j);
        }
        int o = (nl << 9) + (ml << 1);
        *(unsigned long long*)((char*)tb + (o ^ ((nl & 7) << 4))) = pk;
      }
    }
    __syncthreads();
    const int dbase = n0 - 2048;
#pragma unroll
    for (int i = 0; i < 8; ++i) {
      int c = i * 512 + t;
      int dl = c >> 5, mc = c & 31;
      int o = (dl << 9) + (mc << 4);
      short8 vv = *(const short8*)((char*)tb + (o ^ ((dl & 7) << 4)));
      *(short8*)(VT + (size_t)(dbase + dl) * L_ + m0 + mc * 8) = vv;
    }
  } else {
#pragma unroll
    for (int mf = 0; mf < 4; ++mf) {
#pragma unroll
      for (int nf = 0; nf < 4; ++nf) {
#pragma unroll
        for (int j = 0; j < 4; ++j) {
          const int m = m0 + wm * 64 + mf * 16 + hi * 4 + j;
          const int n = n0 + wn * 64 + nf * 16 + rl;
          float x = acc[mf][nf][j];
          if (n < 1024) {
            const int h = n >> 6, d = n & 63;
            size_t b = ((size_t)h * L_ + m) * 128;
            QuQv[b + d]      = __float2bfloat16((x + u[n]) * SCALE_);
            QuQv[b + 64 + d] = __float2bfloat16((x + v[n]) * SCALE_);
          } else if (n < 2048) {
            const int n2 = n - 1024;
            Kr[(((size_t)(n2 >> 6)) * L_ + m) * 128 + (n2 & 63)] = __float2bfloat16(x);
          } else {
            const int c = n - 3072;
            Kr[(((size_t)(c >> 6)) * L_ + m) * 128 + 64 + (c & 63)] = __float2bfloat16(x);
          }
        }
      }
    }
  }
}

// Fused causal attention: LDS-staged K/V (KBLK=64), T14 async-STAGE, setprio.
__global__ __launch_bounds__(256)
void attn_fused(const bf16* __restrict__ QuQv, const bf16* __restrict__ Kr,
                const bf16* __restrict__ VT, bf16* __restrict__ av)
{
  __shared__ __align__(16) bf16 Kt[KBLK * 128];
  __shared__ __align__(16) bf16 Vt[DH_ * KBLK];
  __shared__ __align__(16) bf16 Pt[4][16 * KBLK];

  const int bid = blockIdx.x;
  const int tile = (bid < 256) ? (31 - (bid >> 4)) : ((bid - 256) >> 4);
  const int head = bid & 15;
  const int q0 = tile * 64;
  const int t = threadIdx.x, lane = t & 63, w = t >> 6;
  const int rl = lane & 15, hi = lane >> 4;

  const bf16* Qh = QuQv + (size_t)head * L_ * 128;
  const bf16* Kh = Kr   + (size_t)head * L_ * 128;
  const bf16* Vh = VT   + (size_t)head * DH_ * L_;

  const int qw0 = q0 + w * 16;

  short8 qf[4];
#pragma unroll
  for (int ks = 0; ks < 4; ++ks)
    qf[ks] = *(const short8*)(Qh + (size_t)(qw0 + rl) * 128 + ks * 32 + hi * 8);

  f32x4 o[4];
  float m_r[4], l_r[4];
#pragma unroll
  for (int j = 0; j < 4; ++j) { m_r[j] = -INFINITY; l_r[j] = 0.f; }
#pragma unroll
  for (int fn = 0; fn < 4; ++fn) o[fn] = (f32x4){0.f, 0.f, 0.f, 0.f};

  short8 kreg[4], vreg[2];
  auto load_regs = [&](int k0) {
#pragma unroll
    for (int i = 0; i < 4; ++i) {
      int c = i * 256 + t;
      int row = c >> 4, d8 = (c & 15) << 3;
      kreg[i] = *(const short8*)(Kh + (size_t)(k0 + row) * 128 + d8);
    }
#pragma unroll
    for (int i = 0; i < 2; ++i) {
      int c = i * 256 + t;
      int d = c >> 3, k8 = (c & 7) << 3;
      vreg[i] = *(const short8*)(Vh + (size_t)d * L_ + k0 + k8);
    }
  };
  auto write_lds = [&]() {
#pragma unroll
    for (int i = 0; i < 4; ++i) {
      int c = i * 256 + t;
      int row = c >> 4, d8 = (c & 15) << 3;
      int off = (row << 8) + (((d8 << 1)) ^ ((row & 7) << 4));
      *(short8*)((char*)Kt + off) = kreg[i];
    }
#pragma unroll
    for (int i = 0; i < 2; ++i) {
      int c = i * 256 + t;
      int d = c >> 3, k8 = (c & 7) << 3;
      int off = (d << 7) + (((k8 << 1)) ^ ((d & 7) << 4));
      *(short8*)((char*)Vt + off) = vreg[i];
    }
  };

  load_regs(0);
  write_lds();
  __syncthreads();

  const int kend = q0 + 64;
  for (int k0 = 0; k0 < kend; k0 += KBLK) {
    const bool more = (k0 + KBLK) < kend;
    if (more) load_regs(k0 + KBLK);

    if (k0 <= qw0 + 15) {
      f32x4 s[4];
#pragma unroll
      for (int fn = 0; fn < 4; ++fn) s[fn] = (f32x4){0.f, 0.f, 0.f, 0.f};
      __builtin_amdgcn_s_setprio(1);
#pragma unroll
      for (int fn = 0; fn < 4; ++fn) {
        const int krow = fn * 16 + rl;
#pragma unroll
        for (int ks = 0; ks < 4; ++ks) {
          short8 kf = *(const short8*)((char*)Kt + (krow << 8) +
                        ((((ks * 32 + hi * 8) << 1)) ^ ((krow & 7) << 4)));
          s[fn] = __builtin_amdgcn_mfma_f32_16x16x32_bf16(qf[ks], kf, s[fn], 0, 0, 0);
        }
      }
      __builtin_amdgcn_s_setprio(0);
      if (k0 + KBLK > q0) {
#pragma unroll
        for (int fn = 0; fn < 4; ++fn) {
          const int key = k0 + fn * 16 + rl;
#pragma unroll
          for (int j = 0; j < 4; ++j)
            if (key > qw0 + hi * 4 + j) s[fn][j] = -1e30f;
        }
      }
      float mx[4];
#pragma unroll
      for (int j = 0; j < 4; ++j)
        mx[j] = fmaxf(fmaxf(s[0][j], s[1][j]), fmaxf(s[2][j], s[3][j]));
#pragma unroll
      for (int off = 1; off < 16; off <<= 1)
#pragma unroll
        for (int j = 0; j < 4; ++j) mx[j] = fmaxf(mx[j], __shfl_xor(mx[j], off));
      float sf[4];
#pragma unroll
      for (int j = 0; j < 4; ++j) {
        float mn = fmaxf(m_r[j], mx[j]);
        sf[j] = exp2f((m_r[j] - mn) * LOG2E_);
        m_r[j] = mn;
      }
      float rs[4] = {0.f, 0.f, 0.f, 0.f};
#pragma unroll
      for (int fn = 0; fn < 4; ++fn) {
#pragma unroll
        for (int j = 0; j < 4; ++j) {
          float p = exp2f((s[fn][j] - m_r[j]) * LOG2E_);
          rs[j] += p;
          int row = hi * 4 + j;
          *(bf16*)((char*)Pt[w] + (row << 7) +
                   ((((fn * 16 + rl) << 1)) ^ ((row & 7) << 4))) = __float2bfloat16(p);
        }
      }
#pragma unroll
      for (int off = 1; off < 16; off <<= 1)
#pragma unroll
        for (int j = 0; j < 4; ++j) rs[j] += __shfl_xor(rs[j], off);
#pragma unroll
      for (int j = 0; j < 4; ++j) l_r[j] = l_r[j] * sf[j] + rs[j];
#pragma unroll
      for (int fn = 0; fn < 4; ++fn)
#pragma unroll
        for (int j = 0; j < 4; ++j) o[fn][j] *= sf[j];

      __builtin_amdgcn_s_setprio(1);
#pragma unroll
      for (int ks2 = 0; ks2 < 2; ++ks2) {
        short8 pa = *(const short8*)((char*)Pt[w] + (rl << 7) +
                      ((ks2 * 64 + hi * 16) ^ ((rl & 7) << 4)));
#pragma unroll
        for (int fn = 0; fn < 4; ++fn) {
          const int drow = fn * 16 + rl;
          short8 vf = *(const short8*)((char*)Vt + (drow << 7) +
                        ((ks2 * 64 + hi * 16) ^ ((drow & 7) << 4)));
          o[fn] = __builtin_amdgcn_mfma_f32_16x16x32_bf16(pa, vf, o[fn], 0, 0, 0);
        }
      }
      __builtin_amdgcn_s_setprio(0);
    }

    if (more) {
      __syncthreads();
      write_lds();
      __syncthreads();
    }
  }

#pragma unroll
  for (int fn = 0; fn < 4; ++fn) {
#pragma unroll
    for (int j = 0; j < 4; ++j) {
      int q = qw0 + hi * 4 + j;
      float vv = o[fn][j] / l_r[j];
      av[(size_t)q * D_ + head * 64 + fn * 16 + rl] = __float2bfloat16(vv);
    }
  }
}

__global__ __launch_bounds__(256)
void embed_k(const int* __restrict__ X, const float* __restrict__ emb,
             float* __restrict__ hout, bf16* __restrict__ hbout)
{
  int idx = blockIdx.x * 256 + threadIdx.x;
  if (idx >= L_ * D_) return;
  int tpos = idx >> 10, d = idx & 1023;
  float vv = emb[(size_t)X[tpos] * D_ + d];
  hout[idx] = vv;
  hbout[idx] = __float2bfloat16(vv);
}

__global__ __launch_bounds__(256)
void pe_k(bf16* __restrict__ pe)
{
  int idx = blockIdx.x * 256 + threadIdx.x;
  if (idx >= L_ * D_) return;
  int k = idx >> 10, i = idx & 1023;
  int f = (i < 512) ? i : (i - 512);
  float invf = exp2f(-(float)(2 * f) * (13.28771238f / 1024.f));
  float pp = (float)(L_ - 1 - k) * invf;
  float vv = (i < 512) ? sinf(pp) : cosf(pp);
  pe[idx] = __float2bfloat16(vv);
}

__global__ __launch_bounds__(256)
void cast_all(const float* __restrict__ wqkv, const float* __restrict__ wpe,
              const float* __restrict__ wout, const float* __restrict__ w1,
              const float* __restrict__ w2,
              bf16* __restrict__ dqkv, bf16* __restrict__ dpe, bf16* __restrict__ dout,
              bf16* __restrict__ d1, bf16* __restrict__ d2)
{
  const int n4 = 13631488 / 4;
  for (int i = blockIdx.x * 256 + threadIdx.x; i < n4; i += gridDim.x * 256) {
    int j = i * 4;
    const float* src; bf16* dst; int o;
    if (j < 3145728)      { src = wqkv; dst = dqkv; o = j; }
    else if (j < 4194304) { src = wpe;  dst = dpe;  o = j - 3145728; }
    else if (j < 5242880) { src = wout; dst = dout; o = j - 4194304; }
    else if (j < 9437184) { src = w1;   dst = d1;   o = j - 5242880; }
    else                  { src = w2;   dst = d2;   o = j - 9437184; }
    float4 vv = *(const float4*)(src + o);
    dst[o + 0] = __float2bfloat16(vv.x);
    dst[o + 1] = __float2bfloat16(vv.y);
    dst[o + 2] = __float2bfloat16(vv.z);
    dst[o + 3] = __float2bfloat16(vv.w);
  }
}

__global__ __launch_bounds__(256)
void cast_bf4(const float* __restrict__ in, bf16* __restrict__ out, long long n4)
{
  for (long long i = (long long)blockIdx.x * 256 + threadIdx.x; i < n4; i += (long long)gridDim.x * 256) {
    float4 vv = *(const float4*)(in + i * 4);
    out[i * 4 + 0] = __float2bfloat16(vv.x);
    out[i * 4 + 1] = __float2bfloat16(vv.y);
    out[i * 4 + 2] = __float2bfloat16(vv.z);
    out[i * 4 + 3] = __float2bfloat16(vv.w);
  }
}

__global__ __launch_bounds__(256)
void ln_residual(const float* __restrict__ resid, const float* __restrict__ parts,
                 int nparts, long long pstride, const float* __restrict__ bias,
                 float* __restrict__ hout, bf16* __restrict__ hbout)
{
  const int row = blockIdx.x;
  const int t = threadIdx.x;
  const int lane = t & 63, w = t >> 6;
  const size_t base = (size_t)row * D_;
  __shared__ float rs[4], rs2[4];
  float4 xv = *(const float4*)(resid + base + t * 4);
  for (int p = 0; p < nparts; ++p) {
    float4 pv = *(const float4*)(parts + (size_t)p * pstride + base + t * 4);
    xv.x += pv.x; xv.y += pv.y; xv.z += pv.z; xv.w += pv.w;
  }
  if (bias) {
    float4 bv = *(const float4*)(bias + t * 4);
    xv.x += bv.x; xv.y += bv.y; xv.z += bv.z; xv.w += bv.w;
  }
  float s = xv.x + xv.y + xv.z + xv.w;
  float s2 = xv.x * xv.x + xv.y * xv.y + xv.z * xv.z + xv.w * xv.w;
#pragma unroll
  for (int off = 32; off; off >>= 1) {
    s += __shfl_down(s, off);
    s2 += __shfl_down(s2, off);
  }
  if (lane == 0) { rs[w] = s; rs2[w] = s2; }
  __syncthreads();
  float S = rs[0] + rs[1] + rs[2] + rs[3];
  float S2 = rs2[0] + rs2[1] + rs2[2] + rs2[3];
  float mean = S * (1.f / D_);
  float var = S2 * (1.f / D_) - mean * mean;
  float inv = 1.f / sqrtf(var + EPS_);
  float4 y;
  y.x = (xv.x - mean) * inv;
  y.y = (xv.y - mean) * inv;
  y.z = (xv.z - mean) * inv;
  y.w = (xv.w - mean) * inv;
  *(float4*)(hout + base + t * 4) = y;
  unsigned long long pk =
      (unsigned long long)__bfloat16_as_ushort(__float2bfloat16(y.x)) |
      ((unsigned long long)__bfloat16_as_ushort(__float2bfloat16(y.y)) << 16) |
      ((unsigned long long)__bfloat16_as_ushort(__float2bfloat16(y.z)) << 32) |
      ((unsigned long long)__bfloat16_as_ushort(__float2bfloat16(y.w)) << 48);
  *(unsigned long long*)(hbout + base + t * 4) = pk;
}

extern "C" void kernel_launch(void* const* d_in, const int* in_sizes, int n_in,
                              void* d_out, int out_size, void* d_ws, size_t ws_size,
                              hipStream_t stream)
{
  (void)in_sizes; (void)n_in; (void)out_size; (void)ws_size;
  const int*   X    = (const int*)d_in[0];
  const float* emb  = (const float*)d_in[2];
  const float* u    = (const float*)d_in[3];
  const float* v    = (const float*)d_in[4];
  const float* Wqkv = (const float*)d_in[5];
  const float* Wpe  = (const float*)d_in[6];
  const float* Wout = (const float*)d_in[7];
  const float* W1   = (const float*)d_in[8];
  const float* b1   = (const float*)d_in[9];
  const float* W2   = (const float*)d_in[10];
  const float* b2   = (const float*)d_in[11];
  const float* Wc   = (const float*)d_in[12];
  const float* bc   = (const float*)d_in[13];
  float* out = (float*)d_out;

  size_t off = 0;
  auto alloc = [&](size_t bytes) {
    void* p = (char*)d_ws + off;
    off += (bytes + 255) & ~(size_t)255;
    return p;
  };
  float* h_f32   = (float*)alloc((size_t)L_ * D_ * 4);
  bf16*  h_bf    = (bf16*) alloc((size_t)L_ * D_ * 2);
  bf16*  pe_bf   = (bf16*) alloc((size_t)L_ * D_ * 2);
  bf16*  QuQv    = (bf16*) alloc((size_t)H_ * L_ * 128 * 2);
  bf16*  Kr      = (bf16*) alloc((size_t)H_ * L_ * 128 * 2);
  bf16*  VT      = (bf16*) alloc((size_t)H_ * DH_ * L_ * 2);
  bf16*  av_bf   = (bf16*) alloc((size_t)L_ * D_ * 2);
  float* part_f  = (float*)alloc((size_t)4 * L_ * D_ * 4);
  bf16*  ff1_bf  = (bf16*) alloc((size_t)L_ * DI_ * 2);
  bf16*  Wc_bf   = (bf16*) alloc((size_t)V_ * D_ * 2);
  bf16*  Wqkv_bf = (bf16*) alloc((size_t)3 * D_ * D_ * 2);
  bf16*  Wpe_bf  = (bf16*) alloc((size_t)D_ * D_ * 2);
  bf16*  Wout_bf = (bf16*) alloc((size_t)D_ * D_ * 2);
  bf16*  W1_bf   = (bf16*) alloc((size_t)DI_ * D_ * 2);
  bf16*  W2_bf   = (bf16*) alloc((size_t)D_ * DI_ * 2);

  const int eb = (L_ * D_ + 255) / 256;
  const long long LD = (long long)L_ * D_;

  embed_k<<<eb, 256, 0, stream>>>(X, emb, h_f32, h_bf);
  pe_k<<<eb, 256, 0, stream>>>(pe_bf);

  dim3 gqkvpe(L_ / 256, 4096 / 128, 1);
  dim3 gout (L_ / 256, D_ / 128, 4);
  dim3 gff1 (L_ / 256, DI_ / 128, 1);

  for (int l = 0; l < NL_; ++l) {
    cast_all<<<2048, 256, 0, stream>>>(
        Wqkv + (size_t)l * 3 * D_ * D_, Wpe + (size_t)l * D_ * D_,
        Wout + (size_t)l * D_ * D_, W1 + (size_t)l * DI_ * D_, W2 + (size_t)l * D_ * DI_,
        Wqkv_bf, Wpe_bf, Wout_bf, W1_bf, W2_bf);

    gemm_qkvpe256<<<gqkvpe, 512, 0, stream>>>(h_bf, pe_bf, Wqkv_bf, Wpe_bf, u, v, QuQv, Kr, VT);

    attn_fused<<<512, 256, 0, stream>>>(QuQv, Kr, VT, av_bf);

    gemm256x128<1><<<gout, 512, 0, stream>>>(av_bf, Wout_bf, part_f, nullptr,
        D_, D_, D_, 256, LD);
    ln_residual<<<L_, 256, 0, stream>>>(h_f32, part_f, 4, LD, nullptr, h_f32, h_bf);

    gemm256x128<0><<<gff1, 512, 0, stream>>>(h_bf, W1_bf, ff1_bf, b1 + (size_t)l * DI_,
        D_, D_, DI_, D_, 0);

    gemm256x128<1><<<gout, 512, 0, stream>>>(ff1_bf, W2_bf, part_f, nullptr,
        DI_, DI_, D_, 1024, LD);
    ln_residual<<<L_, 256, 0, stream>>>(h_f32, part_f, 4, LD, b2 + (size_t)l * D_, h_f32, h_bf);
  }

  cast_bf4<<<2048, 256, 0, stream>>>(Wc, Wc_bf, (long long)V_ * D_ / 4);
  dim3 gl(L_ / 256, V_ / 256, 1);
  gemm256<<<gl, 512, 0, stream>>>(h_bf, Wc_bf, out, bc, D_, D_, V_, D_);
}

// Round 18
// 2723.930 us; speedup vs baseline: 1.0094x; 1.0016x over previous
//
#include <hip/hip_runtime.h>
#include <hip/hip_bf16.h>

#define L_ 2048
#define D_ 1024
#define H_ 16
#define DH_ 64
#define DI_ 4096
#define NL_ 12
#define V_ 32000
#define EPS_ 1e-5f
#define SCALE_ 0.125f
#define LOG2E_ 1.44269504f
#define KBLK 64

typedef __attribute__((ext_vector_type(8))) short short8;
typedef __attribute__((ext_vector_type(4))) float f32x4;
typedef __hip_bfloat16 bf16;

__device__ __forceinline__ void gload_lds16(const void* g, void* l) {
  __builtin_amdgcn_global_load_lds((const __attribute__((address_space(1))) void*)g,
                                   (__attribute__((address_space(3))) void*)l, 16, 0, 0);
}

// swizzle for [row][64 bf16] (128B rows): fold row bits 0-2 into bank bits 2-4. Involution.
#define SWZ_(o) ((o) ^ ((((o) >> 7) & 7) << 4))

// ---------------- 256^2 counted-vmcnt GEMM (logits), BK=64 ----------------
__global__ __launch_bounds__(512)
void gemm256(const bf16* __restrict__ A, const bf16* __restrict__ B,
             float* __restrict__ C, const float* __restrict__ bias,
             int lda, int ldb, int ldc, int K)
{
  __shared__ __align__(16) bf16 As[2][256 * 64];
  __shared__ __align__(16) bf16 Bs[2][256 * 64];

  const int gx = gridDim.x;
  const int nwg = gx * gridDim.y;
  const int orig = blockIdx.x + gx * blockIdx.y;
  const int qq = nwg >> 3, rr = nwg & 7;
  const int xcd = orig & 7, sidx = orig >> 3;
  const int lin = (xcd < rr ? xcd * (qq + 1) : rr * (qq + 1) + (xcd - rr) * qq) + sidx;
  const int m0 = (lin % gx) * 256;
  const int n0 = (lin / gx) * 256;

  const int t = threadIdx.x;
  const int lane = t & 63, w = t >> 6;
  const int wm = w >> 2, wn = w & 3;
  const int rl = lane & 15, hi = lane >> 4;

  int srow[4], skb[4];
#pragma unroll
  for (int r = 0; r < 4; ++r) {
    int o = r * 8192 + t * 16;
    int s = SWZ_(o);
    srow[r] = s >> 7;
    skb[r] = s & 127;
  }

  auto stage = [&](int c, int kt) {
    const int k0 = kt * 64;
#pragma unroll
    for (int r = 0; r < 4; ++r)
      gload_lds16((const char*)A + ((size_t)(m0 + srow[r]) * lda + k0) * 2 + skb[r],
                  (char*)As[c] + r * 8192 + w * 1024);
#pragma unroll
    for (int r = 0; r < 4; ++r)
      gload_lds16((const char*)B + ((size_t)(n0 + srow[r]) * ldb + k0) * 2 + skb[r],
                  (char*)Bs[c] + r * 8192 + w * 1024);
  };

  f32x4 acc[8][4];
#pragma unroll
  for (int i = 0; i < 8; ++i)
#pragma unroll
    for (int j = 0; j < 4; ++j) acc[i][j] = (f32x4){0.f, 0.f, 0.f, 0.f};

  const int NT = K >> 6;
  stage(0, 0);
  stage(1, 1);
  asm volatile("s_waitcnt vmcnt(8)" ::: "memory");
  __builtin_amdgcn_s_barrier();
  asm volatile("" ::: "memory");

  int cur = 0;
  for (int kt = 0; kt < NT; ++kt) {
    short8 b[4][2];
#pragma unroll
    for (int nf = 0; nf < 4; ++nf)
#pragma unroll
      for (int ks = 0; ks < 2; ++ks) {
        int l = ((wn * 64 + nf * 16 + rl) << 7) + ks * 64 + hi * 16;
        b[nf][ks] = *(const short8*)((char*)Bs[cur] + SWZ_(l));
      }
#pragma unroll
    for (int p = 0; p < 4; ++p) {
      short8 a[2][2];
#pragma unroll
      for (int i = 0; i < 2; ++i)
#pragma unroll
        for (int ks = 0; ks < 2; ++ks) {
          int l = ((wm * 128 + (2 * p + i) * 16 + rl) << 7) + ks * 64 + hi * 16;
          a[i][ks] = *(const short8*)((char*)As[cur] + SWZ_(l));
        }
      __builtin_amdgcn_s_setprio(1);
#pragma unroll
      for (int i = 0; i < 2; ++i)
#pragma unroll
        for (int nf = 0; nf < 4; ++nf) {
          acc[2 * p + i][nf] = __builtin_amdgcn_mfma_f32_16x16x32_bf16(a[i][0], b[nf][0], acc[2 * p + i][nf], 0, 0, 0);
          acc[2 * p + i][nf] = __builtin_amdgcn_mfma_f32_16x16x32_bf16(a[i][1], b[nf][1], acc[2 * p + i][nf], 0, 0, 0);
        }
      __builtin_amdgcn_s_setprio(0);
    }
    __builtin_amdgcn_s_barrier();
    asm volatile("" ::: "memory");
    if (kt + 2 < NT) stage(cur, kt + 2);
    if (kt + 1 < NT) {
      if (kt + 2 < NT) asm volatile("s_waitcnt vmcnt(8)" ::: "memory");
      else             asm volatile("s_waitcnt vmcnt(0)" ::: "memory");
      __builtin_amdgcn_s_barrier();
      asm volatile("" ::: "memory");
    }
    cur ^= 1;
  }

#pragma unroll
  for (int mf = 0; mf < 8; ++mf) {
#pragma unroll
    for (int nf = 0; nf < 4; ++nf) {
#pragma unroll
      for (int j = 0; j < 4; ++j) {
        const int m = m0 + wm * 128 + mf * 16 + hi * 4 + j;
        const int n = n0 + wn * 64 + nf * 16 + rl;
        C[(size_t)m * ldc + n] = acc[mf][nf][j] + bias[n];
      }
    }
  }
}

// ---------------- 256x128 counted-vmcnt GEMM (layer GEMMs, 2-buffer) ----------------
template<int EPI>
__global__ __launch_bounds__(512)
void gemm256x128(const bf16* __restrict__ A, const bf16* __restrict__ B,
                 void* __restrict__ C, const float* __restrict__ bias,
                 int lda, int ldb, int ldc, int Kc, long long Cstride)
{
  __shared__ __align__(16) bf16 As[2][256 * 64];
  __shared__ __align__(16) bf16 Bs[2][128 * 64];

  const int gx = gridDim.x;
  const int nwg = gx * gridDim.y;
  const int orig = blockIdx.x + gx * blockIdx.y;
  const int qq = nwg >> 3, rr = nwg & 7;
  const int xcd = orig & 7, sidx = orig >> 3;
  const int lin = (xcd < rr ? xcd * (qq + 1) : rr * (qq + 1) + (xcd - rr) * qq) + sidx;
  const int m0 = (lin % gx) * 256;
  const int n0 = (lin / gx) * 128;

  const int kbeg = blockIdx.z * Kc;
  const size_t czoff = (size_t)blockIdx.z * (size_t)Cstride;

  const int t = threadIdx.x;
  const int lane = t & 63, w = t >> 6;
  const int wm = w >> 1, wn = w & 1;   // 4M x 2N
  const int rl = lane & 15, hi = lane >> 4;

  int srow[4], skb[4];
#pragma unroll
  for (int r = 0; r < 4; ++r) {
    int o = r * 8192 + t * 16;
    int s = SWZ_(o);
    srow[r] = s >> 7;
    skb[r] = s & 127;
  }

  auto stage = [&](int c, int kt) {
    const int k0 = kbeg + kt * 64;
#pragma unroll
    for (int r = 0; r < 4; ++r)
      gload_lds16((const char*)A + ((size_t)(m0 + srow[r]) * lda + k0) * 2 + skb[r],
                  (char*)As[c] + r * 8192 + w * 1024);
#pragma unroll
    for (int r = 0; r < 2; ++r)
      gload_lds16((const char*)B + ((size_t)(n0 + srow[r]) * ldb + k0) * 2 + skb[r],
                  (char*)Bs[c] + r * 8192 + w * 1024);
  };

  f32x4 acc[4][4];
#pragma unroll
  for (int i = 0; i < 4; ++i)
#pragma unroll
    for (int j = 0; j < 4; ++j) acc[i][j] = (f32x4){0.f, 0.f, 0.f, 0.f};

  const int NT = Kc >> 6;
  stage(0, 0);
  stage(1, 1);
  asm volatile("s_waitcnt vmcnt(6)" ::: "memory");
  __builtin_amdgcn_s_barrier();
  asm volatile("" ::: "memory");

  int cur = 0;
  for (int kt = 0; kt < NT; ++kt) {
    short8 b[4][2];
#pragma unroll
    for (int nf = 0; nf < 4; ++nf)
#pragma unroll
      for (int ks = 0; ks < 2; ++ks) {
        int l = ((wn * 64 + nf * 16 + rl) << 7) + ks * 64 + hi * 16;
        b[nf][ks] = *(const short8*)((char*)Bs[cur] + SWZ_(l));
      }
#pragma unroll
    for (int p = 0; p < 4; ++p) {
      short8 a[2];
#pragma unroll
      for (int ks = 0; ks < 2; ++ks) {
        int l = ((wm * 64 + p * 16 + rl) << 7) + ks * 64 + hi * 16;
        a[ks] = *(const short8*)((char*)As[cur] + SWZ_(l));
      }
      __builtin_amdgcn_s_setprio(1);
#pragma unroll
      for (int nf = 0; nf < 4; ++nf) {
        acc[p][nf] = __builtin_amdgcn_mfma_f32_16x16x32_bf16(a[0], b[nf][0], acc[p][nf], 0, 0, 0);
        acc[p][nf] = __builtin_amdgcn_mfma_f32_16x16x32_bf16(a[1], b[nf][1], acc[p][nf], 0, 0, 0);
      }
      __builtin_amdgcn_s_setprio(0);
    }
    __builtin_amdgcn_s_barrier();
    asm volatile("" ::: "memory");
    if (kt + 2 < NT) stage(cur, kt + 2);
    if (kt + 1 < NT) {
      if (kt + 2 < NT) asm volatile("s_waitcnt vmcnt(6)" ::: "memory");
      else             asm volatile("s_waitcnt vmcnt(0)" ::: "memory");
      __builtin_amdgcn_s_barrier();
      asm volatile("" ::: "memory");
    }
    cur ^= 1;
  }

#pragma unroll
  for (int mf = 0; mf < 4; ++mf) {
#pragma unroll
    for (int nf = 0; nf < 4; ++nf) {
#pragma unroll
      for (int j = 0; j < 4; ++j) {
        const int m = m0 + wm * 64 + mf * 16 + hi * 4 + j;
        const int n = n0 + wn * 64 + nf * 16 + rl;
        if (EPI == 0) {
          float vv = fmaxf(acc[mf][nf][j] + bias[n], 0.f);
          ((bf16*)C)[(size_t)m * ldc + n] = __float2bfloat16(vv);
        } else {
          ((float*)C)[czoff + (size_t)m * ldc + n] = acc[mf][nf][j];
        }
      }
    }
  }
}

// ---------------- 256x128 qkv+pe GEMM (2-buffer, fused V-transpose epilogue) ----------------
__global__ __launch_bounds__(512)
void gemm_qkvpe256(const bf16* __restrict__ Ah, const bf16* __restrict__ Ape,
                   const bf16* __restrict__ Wqkv, const bf16* __restrict__ Wpe,
                   const float* __restrict__ u, const float* __restrict__ v,
                   bf16* __restrict__ QuQv, bf16* __restrict__ Kr, bf16* __restrict__ VT)
{
  __shared__ __align__(16) bf16 As[2][256 * 64];
  __shared__ __align__(16) bf16 Bs[2][128 * 64];

  const int gx = gridDim.x;
  const int nwg = gx * gridDim.y;
  const int orig = blockIdx.x + gx * blockIdx.y;
  const int qq = nwg >> 3, rr = nwg & 7;
  const int xcd = orig & 7, sidx = orig >> 3;
  const int lin = (xcd < rr ? xcd * (qq + 1) : rr * (qq + 1) + (xcd - rr) * qq) + sidx;
  const int m0 = (lin % gx) * 256;
  const int n0 = (lin / gx) * 128;

  const bf16* Ab = (n0 < 3072) ? Ah : Ape;
  const bf16* Bb = (n0 < 3072) ? (Wqkv + (size_t)n0 * D_) : (Wpe + (size_t)(n0 - 3072) * D_);

  const int t = threadIdx.x;
  const int lane = t & 63, w = t >> 6;
  const int wm = w >> 1, wn = w & 1;
  const int rl = lane & 15, hi = lane >> 4;

  int srow[4], skb[4];
#pragma unroll
  for (int r = 0; r < 4; ++r) {
    int o = r * 8192 + t * 16;
    int s = SWZ_(o);
    srow[r] = s >> 7;
    skb[r] = s & 127;
  }

  auto stage = [&](int c, int kt) {
    const int k0 = kt * 64;
#pragma unroll
    for (int r = 0; r < 4; ++r)
      gload_lds16((const char*)Ab + ((size_t)(m0 + srow[r]) * D_ + k0) * 2 + skb[r],
                  (char*)As[c] + r * 8192 + w * 1024);
#pragma unroll
    for (int r = 0; r < 2; ++r)
      gload_lds16((const char*)Bb + ((size_t)srow[r] * D_ + k0) * 2 + skb[r],
                  (char*)Bs[c] + r * 8192 + w * 1024);
  };

  f32x4 acc[4][4];
#pragma unroll
  for (int i = 0; i < 4; ++i)
#pragma unroll
    for (int j = 0; j < 4; ++j) acc[i][j] = (f32x4){0.f, 0.f, 0.f, 0.f};

  const int NT = D_ >> 6;   // 16
  stage(0, 0);
  stage(1, 1);
  asm volatile("s_waitcnt vmcnt(6)" ::: "memory");
  __builtin_amdgcn_s_barrier();
  asm volatile("" ::: "memory");

  int cur = 0;
  for (int kt = 0; kt < NT; ++kt) {
    short8 b[4][2];
#pragma unroll
    for (int nf = 0; nf < 4; ++nf)
#pragma unroll
      for (int ks = 0; ks < 2; ++ks) {
        int l = ((wn * 64 + nf * 16 + rl) << 7) + ks * 64 + hi * 16;
        b[nf][ks] = *(const short8*)((char*)Bs[cur] + SWZ_(l));
      }
#pragma unroll
    for (int p = 0; p < 4; ++p) {
      short8 a[2];
#pragma unroll
      for (int ks = 0; ks < 2; ++ks) {
        int l = ((wm * 64 + p * 16 + rl) << 7) + ks * 64 + hi * 16;
        a[ks] = *(const short8*)((char*)As[cur] + SWZ_(l));
      }
      __builtin_amdgcn_s_setprio(1);
#pragma unroll
      for (int nf = 0; nf < 4; ++nf) {
        acc[p][nf] = __builtin_amdgcn_mfma_f32_16x16x32_bf16(a[0], b[nf][0], acc[p][nf], 0, 0, 0);
        acc[p][nf] = __builtin_amdgcn_mfma_f32_16x16x32_bf16(a[1], b[nf][1], acc[p][nf], 0, 0, 0);
      }
      __builtin_amdgcn_s_setprio(0);
    }
    __builtin_amdgcn_s_barrier();
    asm volatile("" ::: "memory");
    if (kt + 2 < NT) stage(cur, kt + 2);
    if (kt + 1 < NT) {
      if (kt + 2 < NT) asm volatile("s_waitcnt vmcnt(6)" ::: "memory");
      else             asm volatile("s_waitcnt vmcnt(0)" ::: "memory");
      __builtin_amdgcn_s_barrier();
      asm volatile("" ::: "memory");
    }
    cur ^= 1;
  }

  if (n0 >= 2048 && n0 < 3072) {
    bf16* tb = (bf16*)As;
    __syncthreads();
#pragma unroll
    for (int mf = 0; mf < 4; ++mf) {
#pragma unroll
      for (int nf = 0; nf < 4; ++nf) {
        const int nl = wn * 64 + nf * 16 + rl;
        const int ml = wm * 64 + mf * 16 + hi * 4;
        unsigned long long pk = 0;
#pragma unroll
        for (int j = 0; j < 4; ++j) {
          unsigned short b16 = __bfloat16_as_ushort(__float2bfloat16(acc[mf][nf][j]));
          pk |= (unsigned long long)b16 << (16 * j);
        }
        int o = (nl << 9) + (ml << 1);
        *(unsigned long long*)((char*)tb + (o ^ ((nl & 7) << 4))) = pk;
      }
    }
    __syncthreads();
    const int dbase = n0 - 2048;
#pragma unroll
    for (int i = 0; i < 8; ++i) {
      int c = i * 512 + t;
      int dl = c >> 5, mc = c & 31;
      int o = (dl << 9) + (mc << 4);
      short8 vv = *(const short8*)((char*)tb + (o ^ ((dl & 7) << 4)));
      *(short8*)(VT + (size_t)(dbase + dl) * L_ + m0 + mc * 8) = vv;
    }
  } else {
#pragma unroll
    for (int mf = 0; mf < 4; ++mf) {
#pragma unroll
      for (int nf = 0; nf < 4; ++nf) {
#pragma unroll
        for (int j = 0; j < 4; ++j) {
          const int m = m0 + wm * 64 + mf * 16 + hi * 4 + j;
          const int n = n0 + wn * 64 + nf * 16 + rl;
          float x = acc[mf][nf][j];
          if (n < 1024) {
            const int h = n >> 6, d = n & 63;
            size_t b = ((size_t)h * L_ + m) * 128;
            QuQv[b + d]      = __float2bfloat16((x + u[n]) * SCALE_);
            QuQv[b + 64 + d] = __float2bfloat16((x + v[n]) * SCALE_);
          } else if (n < 2048) {
            const int n2 = n - 1024;
            Kr[(((size_t)(n2 >> 6)) * L_ + m) * 128 + (n2 & 63)] = __float2bfloat16(x);
          } else {
            const int c = n - 3072;
            Kr[(((size_t)(c >> 6)) * L_ + m) * 128 + 64 + (c & 63)] = __float2bfloat16(x);
          }
        }
      }
    }
  }
}

// Fused causal attention: LDS-staged K/V (KBLK=64), T14 async-STAGE, setprio.
__global__ __launch_bounds__(256)
void attn_fused(const bf16* __restrict__ QuQv, const bf16* __restrict__ Kr,
                const bf16* __restrict__ VT, bf16* __restrict__ av)
{
  __shared__ __align__(16) bf16 Kt[KBLK * 128];
  __shared__ __align__(16) bf16 Vt[DH_ * KBLK];
  __shared__ __align__(16) bf16 Pt[4][16 * KBLK];

  const int bid = blockIdx.x;
  const int tile = (bid < 256) ? (31 - (bid >> 4)) : ((bid - 256) >> 4);
  const int head = bid & 15;
  const int q0 = tile * 64;
  const int t = threadIdx.x, lane = t & 63, w = t >> 6;
  const int rl = lane & 15, hi = lane >> 4;

  const bf16* Qh = QuQv + (size_t)head * L_ * 128;
  const bf16* Kh = Kr   + (size_t)head * L_ * 128;
  const bf16* Vh = VT   + (size_t)head * DH_ * L_;

  const int qw0 = q0 + w * 16;

  short8 qf[4];
#pragma unroll
  for (int ks = 0; ks < 4; ++ks)
    qf[ks] = *(const short8*)(Qh + (size_t)(qw0 + rl) * 128 + ks * 32 + hi * 8);

  f32x4 o[4];
  float m_r[4], l_r[4];
#pragma unroll
  for (int j = 0; j < 4; ++j) { m_r[j] = -INFINITY; l_r[j] = 0.f; }
#pragma unroll
  for (int fn = 0; fn < 4; ++fn) o[fn] = (f32x4){0.f, 0.f, 0.f, 0.f};

  short8 kreg[4], vreg[2];
  auto load_regs = [&](int k0) {
#pragma unroll
    for (int i = 0; i < 4; ++i) {
      int c = i * 256 + t;
      int row = c >> 4, d8 = (c & 15) << 3;
      kreg[i] = *(const short8*)(Kh + (size_t)(k0 + row) * 128 + d8);
    }
#pragma unroll
    for (int i = 0; i < 2; ++i) {
      int c = i * 256 + t;
      int d = c >> 3, k8 = (c & 7) << 3;
      vreg[i] = *(const short8*)(Vh + (size_t)d * L_ + k0 + k8);
    }
  };
  auto write_lds = [&]() {
#pragma unroll
    for (int i = 0; i < 4; ++i) {
      int c = i * 256 + t;
      int row = c >> 4, d8 = (c & 15) << 3;
      int off = (row << 8) + (((d8 << 1)) ^ ((row & 7) << 4));
      *(short8*)((char*)Kt + off) = kreg[i];
    }
#pragma unroll
    for (int i = 0; i < 2; ++i) {
      int c = i * 256 + t;
      int d = c >> 3, k8 = (c & 7) << 3;
      int off = (d << 7) + (((k8 << 1)) ^ ((d & 7) << 4));
      *(short8*)((char*)Vt + off) = vreg[i];
    }
  };

  load_regs(0);
  write_lds();
  __syncthreads();

  const int kend = q0 + 64;
  for (int k0 = 0; k0 < kend; k0 += KBLK) {
    const bool more = (k0 + KBLK) < kend;
    if (more) load_regs(k0 + KBLK);

    if (k0 <= qw0 + 15) {
      f32x4 s[4];
#pragma unroll
      for (int fn = 0; fn < 4; ++fn) s[fn] = (f32x4){0.f, 0.f, 0.f, 0.f};
      __builtin_amdgcn_s_setprio(1);
#pragma unroll
      for (int fn = 0; fn < 4; ++fn) {
        const int krow = fn * 16 + rl;
#pragma unroll
        for (int ks = 0; ks < 4; ++ks) {
          short8 kf = *(const short8*)((char*)Kt + (krow << 8) +
                        ((((ks * 32 + hi * 8) << 1)) ^ ((krow & 7) << 4)));
          s[fn] = __builtin_amdgcn_mfma_f32_16x16x32_bf16(qf[ks], kf, s[fn], 0, 0, 0);
        }
      }
      __builtin_amdgcn_s_setprio(0);
      if (k0 + KBLK > q0) {
#pragma unroll
        for (int fn = 0; fn < 4; ++fn) {
          const int key = k0 + fn * 16 + rl;
#pragma unroll
          for (int j = 0; j < 4; ++j)
            if (key > qw0 + hi * 4 + j) s[fn][j] = -1e30f;
        }
      }
      float mx[4];
#pragma unroll
      for (int j = 0; j < 4; ++j)
        mx[j] = fmaxf(fmaxf(s[0][j], s[1][j]), fmaxf(s[2][j], s[3][j]));
#pragma unroll
      for (int off = 1; off < 16; off <<= 1)
#pragma unroll
        for (int j = 0; j < 4; ++j) mx[j] = fmaxf(mx[j], __shfl_xor(mx[j], off));
      float sf[4];
#pragma unroll
      for (int j = 0; j < 4; ++j) {
        float mn = fmaxf(m_r[j], mx[j]);
        sf[j] = exp2f((m_r[j] - mn) * LOG2E_);
        m_r[j] = mn;
      }
      float rs[4] = {0.f, 0.f, 0.f, 0.f};
#pragma unroll
      for (int fn = 0; fn < 4; ++fn) {
#pragma unroll
        for (int j = 0; j < 4; ++j) {
          float p = exp2f((s[fn][j] - m_r[j]) * LOG2E_);
          rs[j] += p;
          int row = hi * 4 + j;
          *(bf16*)((char*)Pt[w] + (row << 7) +
                   ((((fn * 16 + rl) << 1)) ^ ((row & 7) << 4))) = __float2bfloat16(p);
        }
      }
#pragma unroll
      for (int off = 1; off < 16; off <<= 1)
#pragma unroll
        for (int j = 0; j < 4; ++j) rs[j] += __shfl_xor(rs[j], off);
#pragma unroll
      for (int j = 0; j < 4; ++j) l_r[j] = l_r[j] * sf[j] + rs[j];
#pragma unroll
      for (int fn = 0; fn < 4; ++fn)
#pragma unroll
        for (int j = 0; j < 4; ++j) o[fn][j] *= sf[j];

      __builtin_amdgcn_s_setprio(1);
#pragma unroll
      for (int ks2 = 0; ks2 < 2; ++ks2) {
        short8 pa = *(const short8*)((char*)Pt[w] + (rl << 7) +
                      ((ks2 * 64 + hi * 16) ^ ((rl & 7) << 4)));
#pragma unroll
        for (int fn = 0; fn < 4; ++fn) {
          const int drow = fn * 16 + rl;
          short8 vf = *(const short8*)((char*)Vt + (drow << 7) +
                        ((ks2 * 64 + hi * 16) ^ ((drow & 7) << 4)));
          o[fn] = __builtin_amdgcn_mfma_f32_16x16x32_bf16(pa, vf, o[fn], 0, 0, 0);
        }
      }
      __builtin_amdgcn_s_setprio(0);
    }

    if (more) {
      __syncthreads();
      write_lds();
      __syncthreads();
    }
  }

#pragma unroll
  for (int fn = 0; fn < 4; ++fn) {
#pragma unroll
    for (int j = 0; j < 4; ++j) {
      int q = qw0 + hi * 4 + j;
      float vv = o[fn][j] / l_r[j];
      av[(size_t)q * D_ + head * 64 + fn * 16 + rl] = __float2bfloat16(vv);
    }
  }
}

__global__ __launch_bounds__(256)
void embed_k(const int* __restrict__ X, const float* __restrict__ emb,
             float* __restrict__ hout, bf16* __restrict__ hbout)
{
  int idx = blockIdx.x * 256 + threadIdx.x;
  if (idx >= L_ * D_) return;
  int tpos = idx >> 10, d = idx & 1023;
  float vv = emb[(size_t)X[tpos] * D_ + d];
  hout[idx] = vv;
  hbout[idx] = __float2bfloat16(vv);
}

__global__ __launch_bounds__(256)
void pe_k(bf16* __restrict__ pe)
{
  int idx = blockIdx.x * 256 + threadIdx.x;
  if (idx >= L_ * D_) return;
  int k = idx >> 10, i = idx & 1023;
  int f = (i < 512) ? i : (i - 512);
  float invf = exp2f(-(float)(2 * f) * (13.28771238f / 1024.f));
  float pp = (float)(L_ - 1 - k) * invf;
  float vv = (i < 512) ? sinf(pp) : cosf(pp);
  pe[idx] = __float2bfloat16(vv);
}

__global__ __launch_bounds__(256)
void cast_all(const float* __restrict__ wqkv, const float* __restrict__ wpe,
              const float* __restrict__ wout, const float* __restrict__ w1,
              const float* __restrict__ w2,
              bf16* __restrict__ dqkv, bf16* __restrict__ dpe, bf16* __restrict__ dout,
              bf16* __restrict__ d1, bf16* __restrict__ d2)
{
  const int n4 = 13631488 / 4;
  for (int i = blockIdx.x * 256 + threadIdx.x; i < n4; i += gridDim.x * 256) {
    int j = i * 4;
    const float* src; bf16* dst; int o;
    if (j < 3145728)      { src = wqkv; dst = dqkv; o = j; }
    else if (j < 4194304) { src = wpe;  dst = dpe;  o = j - 3145728; }
    else if (j < 5242880) { src = wout; dst = dout; o = j - 4194304; }
    else if (j < 9437184) { src = w1;   dst = d1;   o = j - 5242880; }
    else                  { src = w2;   dst = d2;   o = j - 9437184; }
    float4 vv = *(const float4*)(src + o);
    dst[o + 0] = __float2bfloat16(vv.x);
    dst[o + 1] = __float2bfloat16(vv.y);
    dst[o + 2] = __float2bfloat16(vv.z);
    dst[o + 3] = __float2bfloat16(vv.w);
  }
}

__global__ __launch_bounds__(256)
void cast_bf4(const float* __restrict__ in, bf16* __restrict__ out, long long n4)
{
  for (long long i = (long long)blockIdx.x * 256 + threadIdx.x; i < n4; i += (long long)gridDim.x * 256) {
    float4 vv = *(const float4*)(in + i * 4);
    out[i * 4 + 0] = __float2bfloat16(vv.x);
    out[i * 4 + 1] = __float2bfloat16(vv.y);
    out[i * 4 + 2] = __float2bfloat16(vv.z);
    out[i * 4 + 3] = __float2bfloat16(vv.w);
  }
}

__global__ __launch_bounds__(256)
void ln_residual(const float* __restrict__ resid, const float* __restrict__ parts,
                 int nparts, long long pstride, const float* __restrict__ bias,
                 float* __restrict__ hout, bf16* __restrict__ hbout)
{
  const int row = blockIdx.x;
  const int t = threadIdx.x;
  const int lane = t & 63, w = t >> 6;
  const size_t base = (size_t)row * D_;
  __shared__ float rs[4], rs2[4];
  float4 xv = *(const float4*)(resid + base + t * 4);
  for (int p = 0; p < nparts; ++p) {
    float4 pv = *(const float4*)(parts + (size_t)p * pstride + base + t * 4);
    xv.x += pv.x; xv.y += pv.y; xv.z += pv.z; xv.w += pv.w;
  }
  if (bias) {
    float4 bv = *(const float4*)(bias + t * 4);
    xv.x += bv.x; xv.y += bv.y; xv.z += bv.z; xv.w += bv.w;
  }
  float s = xv.x + xv.y + xv.z + xv.w;
  float s2 = xv.x * xv.x + xv.y * xv.y + xv.z * xv.z + xv.w * xv.w;
#pragma unroll
  for (int off = 32; off; off >>= 1) {
    s += __shfl_down(s, off);
    s2 += __shfl_down(s2, off);
  }
  if (lane == 0) { rs[w] = s; rs2[w] = s2; }
  __syncthreads();
  float S = rs[0] + rs[1] + rs[2] + rs[3];
  float S2 = rs2[0] + rs2[1] + rs2[2] + rs2[3];
  float mean = S * (1.f / D_);
  float var = S2 * (1.f / D_) - mean * mean;
  float inv = 1.f / sqrtf(var + EPS_);
  float4 y;
  y.x = (xv.x - mean) * inv;
  y.y = (xv.y - mean) * inv;
  y.z = (xv.z - mean) * inv;
  y.w = (xv.w - mean) * inv;
  *(float4*)(hout + base + t * 4) = y;
  unsigned long long pk =
      (unsigned long long)__bfloat16_as_ushort(__float2bfloat16(y.x)) |
      ((unsigned long long)__bfloat16_as_ushort(__float2bfloat16(y.y)) << 16) |
      ((unsigned long long)__bfloat16_as_ushort(__float2bfloat16(y.z)) << 32) |
      ((unsigned long long)__bfloat16_as_ushort(__float2bfloat16(y.w)) << 48);
  *(unsigned long long*)(hbout + base + t * 4) = pk;
}

extern "C" void kernel_launch(void* const* d_in, const int* in_sizes, int n_in,
                              void* d_out, int out_size, void* d_ws, size_t ws_size,
                              hipStream_t stream)
{
  (void)in_sizes; (void)n_in; (void)out_size; (void)ws_size;
  const int*   X    = (const int*)d_in[0];
  const float* emb  = (const float*)d_in[2];
  const float* u    = (const float*)d_in[3];
  const float* v    = (const float*)d_in[4];
  const float* Wqkv = (const float*)d_in[5];
  const float* Wpe  = (const float*)d_in[6];
  const float* Wout = (const float*)d_in[7];
  const float* W1   = (const float*)d_in[8];
  const float* b1   = (const float*)d_in[9];
  const float* W2   = (const float*)d_in[10];
  const float* b2   = (const float*)d_in[11];
  const float* Wc   = (const float*)d_in[12];
  const float* bc   = (const float*)d_in[13];
  float* out = (float*)d_out;

  size_t off = 0;
  auto alloc = [&](size_t bytes) {
    void* p = (char*)d_ws + off;
    off += (bytes + 255) & ~(size_t)255;
    return p;
  };
  float* h_f32   = (float*)alloc((size_t)L_ * D_ * 4);
  bf16*  h_bf    = (bf16*) alloc((size_t)L_ * D_ * 2);
  bf16*  pe_bf   = (bf16*) alloc((size_t)L_ * D_ * 2);
  bf16*  QuQv    = (bf16*) alloc((size_t)H_ * L_ * 128 * 2);
  bf16*  Kr      = (bf16*) alloc((size_t)H_ * L_ * 128 * 2);
  bf16*  VT      = (bf16*) alloc((size_t)H_ * DH_ * L_ * 2);
  bf16*  av_bf   = (bf16*) alloc((size_t)L_ * D_ * 2);
  float* part_f  = (float*)alloc((size_t)4 * L_ * D_ * 4);
  bf16*  ff1_bf  = (bf16*) alloc((size_t)L_ * DI_ * 2);
  bf16*  Wc_bf   = (bf16*) alloc((size_t)V_ * D_ * 2);
  bf16*  Wqkv_bf = (bf16*) alloc((size_t)3 * D_ * D_ * 2);
  bf16*  Wpe_bf  = (bf16*) alloc((size_t)D_ * D_ * 2);
  bf16*  Wout_bf = (bf16*) alloc((size_t)D_ * D_ * 2);
  bf16*  W1_bf   = (bf16*) alloc((size_t)DI_ * D_ * 2);
  bf16*  W2_bf   = (bf16*) alloc((size_t)D_ * DI_ * 2);

  const int eb = (L_ * D_ + 255) / 256;
  const long long LD = (long long)L_ * D_;

  embed_k<<<eb, 256, 0, stream>>>(X, emb, h_f32, h_bf);
  pe_k<<<eb, 256, 0, stream>>>(pe_bf);

  dim3 gqkvpe(L_ / 256, 4096 / 128, 1);
  dim3 gout (L_ / 256, D_ / 128, 4);
  dim3 gff1 (L_ / 256, DI_ / 128, 1);

  for (int l = 0; l < NL_; ++l) {
    cast_all<<<2048, 256, 0, stream>>>(
        Wqkv + (size_t)l * 3 * D_ * D_, Wpe + (size_t)l * D_ * D_,
        Wout + (size_t)l * D_ * D_, W1 + (size_t)l * DI_ * D_, W2 + (size_t)l * D_ * DI_,
        Wqkv_bf, Wpe_bf, Wout_bf, W1_bf, W2_bf);

    gemm_qkvpe256<<<gqkvpe, 512, 0, stream>>>(h_bf, pe_bf, Wqkv_bf, Wpe_bf, u, v, QuQv, Kr, VT);

    attn_fused<<<512, 256, 0, stream>>>(QuQv, Kr, VT, av_bf);

    gemm256x128<1><<<gout, 512, 0, stream>>>(av_bf, Wout_bf, part_f, nullptr,
        D_, D_, D_, 256, LD);
    ln_residual<<<L_, 256, 0, stream>>>(h_f32, part_f, 4, LD, nullptr, h_f32, h_bf);

    gemm256x128<0><<<gff1, 512, 0, stream>>>(h_bf, W1_bf, ff1_bf, b1 + (size_t)l * DI_,
        D_, D_, DI_, D_, 0);

    gemm256x128<1><<<gout, 512, 0, stream>>>(ff1_bf, W2_bf, part_f, nullptr,
        DI_, DI_, D_, 1024, LD);
    ln_residual<<<L_, 256, 0, stream>>>(h_f32, part_f, 4, LD, b2 + (size_t)l * D_, h_f32, h_bf);
  }

  cast_bf4<<<2048, 256, 0, stream>>>(Wc, Wc_bf, (long long)V_ * D_ / 4);
  dim3 gl(L_ / 256, V_ / 256, 1);
  gemm256<<<gl, 512, 0, stream>>>(h_bf, Wc_bf, out, bc, D_, D_, V_, D_);
}